// Round 7
// baseline (1320.895 us; speedup 1.0000x reference)
//
#include <hip/hip_runtime.h>

#define T_ 10
#define B_ 4
#define N_ 2048
#define NTOT 8192
#define F_ 64
#define H_ 128
#define NHEADS 4
#define D_ 32
#define E_ 65536

typedef unsigned short u16;

__device__ __forceinline__ float sigf(float x){ return 1.f / (1.f + __expf(-x)); }
__device__ __forceinline__ float tanhfast(float x){ return 1.f - 2.f / (__expf(2.f * x) + 1.f); }

// ---------------- CSR build ----------------
__global__ __launch_bounds__(256) void k_init(int* __restrict__ cnt){
  int i = blockIdx.x * 256 + threadIdx.x;
  if(i < NTOT) cnt[i] = 0;
}

__global__ __launch_bounds__(256) void k_count(const int* __restrict__ ei, int* __restrict__ cnt){
  int e = blockIdx.x * 256 + threadIdx.x;
  if(e < E_) atomicAdd(&cnt[ei[E_ + e]], 1);
}

__global__ __launch_bounds__(1024) void k_scan(const int* __restrict__ cnt,
                                               int* __restrict__ rowst,
                                               int* __restrict__ cursor){
  __shared__ int lds[1024];
  const int t = threadIdx.x;
  int loc[8];
  int s = 0;
  #pragma unroll
  for(int i = 0; i < 8; i++){ loc[i] = s; s += cnt[t * 8 + i]; }
  lds[t] = s;
  __syncthreads();
  for(int off = 1; off < 1024; off <<= 1){
    int v = lds[t];
    int a = (t >= off) ? lds[t - off] : 0;
    __syncthreads();
    lds[t] = v + a;
    __syncthreads();
  }
  const int base = (t > 0) ? lds[t - 1] : 0;
  #pragma unroll
  for(int i = 0; i < 8; i++){
    rowst[t * 8 + i] = base + loc[i];
    cursor[t * 8 + i] = 0;
  }
  if(t == 1023) rowst[NTOT] = lds[1023];
}

__global__ __launch_bounds__(256) void k_fill(const int* __restrict__ ei,
                                              const int* __restrict__ rowst,
                                              int* __restrict__ cursor,
                                              int* __restrict__ csr){
  int e = blockIdx.x * 256 + threadIdx.x;
  if(e < E_){
    int d = ei[E_ + e];
    int pos = atomicAdd(&cursor[d], 1);
    csr[rowst[d] + pos] = ei[e];
  }
}

// ---------------- weight transpose (512,128) -> (128,512) ----------------
__global__ __launch_bounds__(256) void k_wt(const float* __restrict__ src, float* __restrict__ dst){
  int i = blockIdx.x * 256 + threadIdx.x;
  if(i < 512 * 128){
    int r = i >> 7, c = i & 127;
    dst[c * 512 + r] = src[i];
  }
}

// ---------------- GAT projection + attention coefficients (pure fp32) ----------------
__global__ __launch_bounds__(128) void k_proj(const float* __restrict__ x,
    const float* __restrict__ W, const float* __restrict__ att_s, const float* __restrict__ att_d,
    float* __restrict__ hbuf, float* __restrict__ asrc, float* __restrict__ adst){
  __shared__ float Wl[F_ * H_];
  __shared__ float xl[8 * F_];
  const int tid = threadIdx.x;
  for(int i = tid; i < F_ * H_; i += 128) Wl[i] = W[i];
  const int r0 = blockIdx.x * 8;
  for(int i = tid; i < 8 * F_; i += 128){
    const int r = i >> 6, f = i & 63;
    const int row = r0 + r;
    const int t = row >> 13, nt = row & 8191;
    const int bb = nt >> 11, n = nt & 2047;
    xl[i] = x[(((size_t)bb * T_ + t) * N_ + n) * F_ + f];
  }
  __syncthreads();
  const int col = tid;  // 0..127
  const float wsv = att_s[col];
  const float wdv = att_d[col];
  for(int r = 0; r < 8; r++){
    float acc = 0.f;
    #pragma unroll
    for(int k = 0; k < F_; k++) acc += xl[r * F_ + k] * Wl[k * H_ + col];
    const int row = r0 + r;
    hbuf[(size_t)row * H_ + col] = acc;
    float vs = acc * wsv, vd = acc * wdv;
    #pragma unroll
    for(int m = 16; m >= 1; m >>= 1){ vs += __shfl_xor(vs, m); vd += __shfl_xor(vd, m); }
    if((tid & 31) == 0){
      const int head = col >> 5;
      asrc[(size_t)row * NHEADS + head] = vs;
      adst[(size_t)row * NHEADS + head] = vd;
    }
  }
}

// ---------------- GAT edge softmax + aggregation (gather, online softmax) ----------------
__global__ __launch_bounds__(256) void k_edge(const float* __restrict__ hbuf,
    const float* __restrict__ asrc, const float* __restrict__ adst,
    const int* __restrict__ rowst, const int* __restrict__ csr,
    const float* __restrict__ gbias, float* __restrict__ spat){
  const int g = blockIdx.x * 256 + threadIdx.x;
  const int task = g >> 5;
  const int ln = g & 31;
  const int head = task & 3;
  const int node = (task >> 2) & 8191;
  const int t = task >> 15;
  const int rbase = t * NTOT;
  const float ad = adst[(size_t)(rbase + node) * NHEADS + head];
  // self-loop first (reference concatenates self-loops)
  float e = asrc[(size_t)(rbase + node) * NHEADS + head] + ad;
  e = e > 0.f ? e : 0.2f * e;
  float m = e, den = 1.f;
  float acc = hbuf[(size_t)(rbase + node) * H_ + head * D_ + ln];
  const int rs = rowst[node], re = rowst[node + 1];
  for(int i = rs; i < re; i++){
    const int s = csr[i];
    float ev = asrc[(size_t)(rbase + s) * NHEADS + head] + ad;
    ev = ev > 0.f ? ev : 0.2f * ev;
    const float hv = hbuf[(size_t)(rbase + s) * H_ + head * D_ + ln];
    const float nm = fmaxf(m, ev);
    const float s1 = __expf(m - nm), s2 = __expf(ev - nm);
    den = den * s1 + s2;
    acc = acc * s1 + s2 * hv;
    m = nm;
  }
  const int col = head * D_ + ln;
  float outv = acc / den + gbias[col];
  spat[(size_t)(rbase + node) * H_ + col] = outv > 0.f ? outv : 0.f;
}

// ---------------- 2-layer LSTM, persistent per-block (16 nodes), pure-VALU fp32 ----------------
__global__ __launch_bounds__(512, 2) void k_lstm(
    const float* __restrict__ spat,
    const float* __restrict__ Wtih0, const float* __restrict__ Wthh0,
    const float* __restrict__ bih0,  const float* __restrict__ bhh0,
    const float* __restrict__ Wtih1, const float* __restrict__ Wthh1,
    const float* __restrict__ bih1,  const float* __restrict__ bhh1,
    float* __restrict__ h1f)
{
  __shared__ __align__(16) float xin[16 * 128];
  __shared__ __align__(16) float h0s[16 * 128];
  __shared__ __align__(16) float h1s[16 * 128];
  __shared__ float gbuf[16 * 513];

  const int tid = threadIdx.x;   // gate col
  const int n0  = blockIdx.x * 16;

  for(int i = tid; i < 16 * 128; i += 512){ h0s[i] = 0.f; h1s[i] = 0.f; }
  float c0[4], c1[4];
  #pragma unroll
  for(int p = 0; p < 4; p++){ c0[p] = 0.f; c1[p] = 0.f; }

  const float bias0 = bih0[tid] + bhh0[tid];
  const float bias1 = bih1[tid] + bhh1[tid];

  #pragma unroll 1
  for(int t = 0; t < T_; t++){
    ((float4*)xin)[tid] = ((const float4*)(spat + ((size_t)t * NTOT + n0) * H_))[tid];
    __syncthreads();

    #pragma unroll 1
    for(int layer = 0; layer < 2; layer++){
      const float* xp = layer ? h0s : xin;
      const float* hp = layer ? h1s : h0s;
      const float* Wi = layer ? Wtih1 : Wtih0;
      const float* Wh = layer ? Wthh1 : Wthh0;
      float acc[16];
      const float bg = layer ? bias1 : bias0;
      #pragma unroll
      for(int n = 0; n < 16; n++) acc[n] = bg;

      #pragma unroll 2
      for(int k = 0; k < 128; k += 4){
        const float wi0 = Wi[(k + 0) * 512 + tid];
        const float wi1 = Wi[(k + 1) * 512 + tid];
        const float wi2 = Wi[(k + 2) * 512 + tid];
        const float wi3 = Wi[(k + 3) * 512 + tid];
        const float wh0 = Wh[(k + 0) * 512 + tid];
        const float wh1 = Wh[(k + 1) * 512 + tid];
        const float wh2 = Wh[(k + 2) * 512 + tid];
        const float wh3 = Wh[(k + 3) * 512 + tid];
        #pragma unroll
        for(int n = 0; n < 16; n++){
          const float4 xv = *(const float4*)&xp[n * 128 + k];
          const float4 hv = *(const float4*)&hp[n * 128 + k];
          acc[n] += wi0 * xv.x + wi1 * xv.y + wi2 * xv.z + wi3 * xv.w
                  + wh0 * hv.x + wh1 * hv.y + wh2 * hv.z + wh3 * hv.w;
        }
      }
      #pragma unroll
      for(int n = 0; n < 16; n++) gbuf[n * 513 + tid] = acc[n];
      __syncthreads();

      float* hcur = layer ? h1s : h0s;
      float* cp   = layer ? c1  : c0;
      #pragma unroll
      for(int p = 0; p < 4; p++){
        const int il = p * 512 + tid;
        const int nl = il >> 7;
        const int dim = il & 127;
        const float gi = gbuf[nl * 513 + dim];
        const float gf = gbuf[nl * 513 + 128 + dim];
        const float gg = gbuf[nl * 513 + 256 + dim];
        const float go = gbuf[nl * 513 + 384 + dim];
        const float c = sigf(gf) * cp[p] + sigf(gi) * tanhfast(gg);
        cp[p] = c;
        const float hv = sigf(go) * tanhfast(c);
        hcur[nl * 128 + dim] = hv;
        if(layer == 1 && t == T_ - 1)
          h1f[(size_t)(n0 + nl) * H_ + dim] = hv;
      }
      __syncthreads();
    }
  }
}

// ---------------- LayerNorm: one wave per node, shuffle-only, fp32 output ----------------
__global__ __launch_bounds__(64) void k_ln(const float* __restrict__ h1f,
    const float* __restrict__ g, const float* __restrict__ b, float* __restrict__ out){
  const int node = blockIdx.x;
  const int tid = threadIdx.x;
  const float v0 = h1f[(size_t)node * H_ + tid];
  const float v1 = h1f[(size_t)node * H_ + 64 + tid];
  float s = v0 + v1;
  #pragma unroll
  for(int m = 32; m >= 1; m >>= 1) s += __shfl_xor(s, m);
  const float mu = s * (1.f / H_);
  const float d0 = v0 - mu, d1 = v1 - mu;
  s = d0 * d0 + d1 * d1;
  #pragma unroll
  for(int m = 32; m >= 1; m >>= 1) s += __shfl_xor(s, m);
  const float rstd = rsqrtf(s * (1.f / H_) + 1e-5f);
  out[(size_t)node * H_ + tid]      = d0 * rstd * g[tid]      + b[tid];
  out[(size_t)node * H_ + 64 + tid] = d1 * rstd * g[64 + tid] + b[64 + tid];
}

extern "C" void kernel_launch(void* const* d_in, const int* in_sizes, int n_in,
                              void* d_out, int out_size, void* d_ws, size_t ws_size,
                              hipStream_t stream) {
  (void)in_sizes; (void)n_in; (void)out_size; (void)ws_size;
  const float* x     = (const float*)d_in[0];
  const float* W     = (const float*)d_in[1];
  const float* att_s = (const float*)d_in[2];
  const float* att_d = (const float*)d_in[3];
  const float* gbias = (const float*)d_in[4];
  const float* Wih0  = (const float*)d_in[5];
  const float* Whh0  = (const float*)d_in[6];
  const float* bih0  = (const float*)d_in[7];
  const float* bhh0  = (const float*)d_in[8];
  const float* Wih1  = (const float*)d_in[9];
  const float* Whh1  = (const float*)d_in[10];
  const float* bih1  = (const float*)d_in[11];
  const float* bhh1  = (const float*)d_in[12];
  const float* lng   = (const float*)d_in[13];
  const float* lnb   = (const float*)d_in[14];
  const int*   ei    = (const int*)d_in[15];
  float* out = (float*)d_out;

  char* p = (char*)d_ws;
  auto carve = [&](size_t bytes) -> void* {
    void* r = (void*)p;
    p += (bytes + 255) & ~(size_t)255;
    return r;
  };
  float* Wtih0 = (float*)carve(512 * 128 * 4);
  float* Wthh0 = (float*)carve(512 * 128 * 4);
  float* Wtih1 = (float*)carve(512 * 128 * 4);
  float* Wthh1 = (float*)carve(512 * 128 * 4);
  float* hbuf  = (float*)carve((size_t)T_ * NTOT * H_ * 4);        // 41.9 MB
  float* asrc  = (float*)carve((size_t)T_ * NTOT * NHEADS * 4);
  float* adst  = (float*)carve((size_t)T_ * NTOT * NHEADS * 4);
  float* h1f   = (float*)carve((size_t)NTOT * H_ * 4);
  float* spat  = (float*)carve((size_t)T_ * NTOT * H_ * 4);        // 41.9 MB
  int*   cnt   = (int*)carve(NTOT * 4);
  int*   curs  = (int*)carve(NTOT * 4);
  int*   rowst = (int*)carve((NTOT + 1) * 4);
  int*   csr   = (int*)carve((size_t)E_ * 4);

  hipLaunchKernelGGL(k_init,  dim3(32),    dim3(256),  0, stream, cnt);
  hipLaunchKernelGGL(k_count, dim3(256),   dim3(256),  0, stream, ei, cnt);
  hipLaunchKernelGGL(k_scan,  dim3(1),     dim3(1024), 0, stream, cnt, rowst, curs);
  hipLaunchKernelGGL(k_fill,  dim3(256),   dim3(256),  0, stream, ei, rowst, curs, csr);
  hipLaunchKernelGGL(k_wt,    dim3(256),   dim3(256),  0, stream, Wih0, Wtih0);
  hipLaunchKernelGGL(k_wt,    dim3(256),   dim3(256),  0, stream, Whh0, Wthh0);
  hipLaunchKernelGGL(k_wt,    dim3(256),   dim3(256),  0, stream, Wih1, Wtih1);
  hipLaunchKernelGGL(k_wt,    dim3(256),   dim3(256),  0, stream, Whh1, Wthh1);
  hipLaunchKernelGGL(k_proj,  dim3(10240), dim3(128),  0, stream, x, W, att_s, att_d, hbuf, asrc, adst);
  hipLaunchKernelGGL(k_edge,  dim3(40960), dim3(256),  0, stream, hbuf, asrc, adst, rowst, csr, gbias, spat);
  hipLaunchKernelGGL(k_lstm,  dim3(512),   dim3(512),  0, stream, spat,
                     Wtih0, Wthh0, bih0, bhh0, Wtih1, Wthh1, bih1, bhh1, h1f);
  hipLaunchKernelGGL(k_ln,    dim3(8192),  dim3(64),   0, stream, h1f, lng, lnb, out);
}

// Round 8
// 540.478 us; speedup vs baseline: 2.4439x; 2.4439x over previous
//
#include <hip/hip_runtime.h>

#define T_ 10
#define B_ 4
#define N_ 2048
#define NTOT 8192
#define F_ 64
#define H_ 128
#define NHEADS 4
#define D_ 32
#define E_ 65536
#define GPAD 516
#define HPAD 136

typedef __bf16 bf16x8 __attribute__((ext_vector_type(8)));
typedef float f32x4 __attribute__((ext_vector_type(4)));
typedef unsigned short u16;

__device__ __forceinline__ u16 f2bf(float f){
  union { float f; unsigned int i; } v; v.f = f;
  return (u16)((v.i + 0x7FFFu + ((v.i >> 16) & 1u)) >> 16);
}
__device__ __forceinline__ float sigf(float x){ return 1.f / (1.f + __expf(-x)); }
__device__ __forceinline__ float tanhfast(float x){ return 1.f - 2.f / (__expf(2.f * x) + 1.f); }

// ---------------- CSR build ----------------
__global__ __launch_bounds__(256) void k_init(int* __restrict__ cnt){
  int i = blockIdx.x * 256 + threadIdx.x;
  if(i < NTOT) cnt[i] = 0;
}

__global__ __launch_bounds__(256) void k_count(const int* __restrict__ ei, int* __restrict__ cnt){
  int e = blockIdx.x * 256 + threadIdx.x;
  if(e < E_) atomicAdd(&cnt[ei[E_ + e]], 1);
}

__global__ __launch_bounds__(1024) void k_scan(const int* __restrict__ cnt,
                                               int* __restrict__ rowst,
                                               int* __restrict__ cursor){
  __shared__ int lds[1024];
  const int t = threadIdx.x;
  int loc[8];
  int s = 0;
  #pragma unroll
  for(int i = 0; i < 8; i++){ loc[i] = s; s += cnt[t * 8 + i]; }
  lds[t] = s;
  __syncthreads();
  for(int off = 1; off < 1024; off <<= 1){
    int v = lds[t];
    int a = (t >= off) ? lds[t - off] : 0;
    __syncthreads();
    lds[t] = v + a;
    __syncthreads();
  }
  const int base = (t > 0) ? lds[t - 1] : 0;
  #pragma unroll
  for(int i = 0; i < 8; i++){
    rowst[t * 8 + i] = base + loc[i];
    cursor[t * 8 + i] = 0;
  }
  if(t == 1023) rowst[NTOT] = lds[1023];
}

__global__ __launch_bounds__(256) void k_fill(const int* __restrict__ ei,
                                              const int* __restrict__ rowst,
                                              int* __restrict__ cursor,
                                              int* __restrict__ csr){
  int e = blockIdx.x * 256 + threadIdx.x;
  if(e < E_){
    int d = ei[E_ + e];
    int pos = atomicAdd(&cursor[d], 1);
    csr[rowst[d] + pos] = ei[e];
  }
}

// ---------------- fp32 -> bf16 weight conversion (512x128) ----------------
__global__ __launch_bounds__(256) void k_wbf(const float* __restrict__ src, u16* __restrict__ dst){
  int i = blockIdx.x * 256 + threadIdx.x;
  if(i < 512 * 128) dst[i] = f2bf(src[i]);
}

// ---------------- GAT projection + attention coefficients (pure fp32) ----------------
__global__ __launch_bounds__(128) void k_proj(const float* __restrict__ x,
    const float* __restrict__ W, const float* __restrict__ att_s, const float* __restrict__ att_d,
    float* __restrict__ hbuf, float* __restrict__ asrc, float* __restrict__ adst){
  __shared__ float Wl[F_ * H_];
  __shared__ float xl[8 * F_];
  const int tid = threadIdx.x;
  for(int i = tid; i < F_ * H_; i += 128) Wl[i] = W[i];
  const int r0 = blockIdx.x * 8;
  for(int i = tid; i < 8 * F_; i += 128){
    const int r = i >> 6, f = i & 63;
    const int row = r0 + r;
    const int t = row >> 13, nt = row & 8191;
    const int bb = nt >> 11, n = nt & 2047;
    xl[i] = x[(((size_t)bb * T_ + t) * N_ + n) * F_ + f];
  }
  __syncthreads();
  const int col = tid;  // 0..127
  const float wsv = att_s[col];
  const float wdv = att_d[col];
  for(int r = 0; r < 8; r++){
    float acc = 0.f;
    #pragma unroll
    for(int k = 0; k < F_; k++) acc += xl[r * F_ + k] * Wl[k * H_ + col];
    const int row = r0 + r;
    hbuf[(size_t)row * H_ + col] = acc;
    float vs = acc * wsv, vd = acc * wdv;
    #pragma unroll
    for(int m = 16; m >= 1; m >>= 1){ vs += __shfl_xor(vs, m); vd += __shfl_xor(vd, m); }
    if((tid & 31) == 0){
      const int head = col >> 5;
      asrc[(size_t)row * NHEADS + head] = vs;
      adst[(size_t)row * NHEADS + head] = vd;
    }
  }
}

// ---------------- GAT edge softmax + aggregation (gather, online softmax) -> bf16 spat ----------------
__global__ __launch_bounds__(256) void k_edge(const float* __restrict__ hbuf,
    const float* __restrict__ asrc, const float* __restrict__ adst,
    const int* __restrict__ rowst, const int* __restrict__ csr,
    const float* __restrict__ gbias, u16* __restrict__ spat){
  const int g = blockIdx.x * 256 + threadIdx.x;
  const int task = g >> 5;
  const int ln = g & 31;
  const int head = task & 3;
  const int node = (task >> 2) & 8191;
  const int t = task >> 15;
  const int rbase = t * NTOT;
  const float ad = adst[(size_t)(rbase + node) * NHEADS + head];
  // self-loop first (reference concatenates self-loops)
  float e = asrc[(size_t)(rbase + node) * NHEADS + head] + ad;
  e = e > 0.f ? e : 0.2f * e;
  float m = e, den = 1.f;
  float acc = hbuf[(size_t)(rbase + node) * H_ + head * D_ + ln];
  const int rs = rowst[node], re = rowst[node + 1];
  for(int i = rs; i < re; i++){
    const int s = csr[i];
    float ev = asrc[(size_t)(rbase + s) * NHEADS + head] + ad;
    ev = ev > 0.f ? ev : 0.2f * ev;
    const float hv = hbuf[(size_t)(rbase + s) * H_ + head * D_ + ln];
    const float nm = fmaxf(m, ev);
    const float s1 = __expf(m - nm), s2 = __expf(ev - nm);
    den = den * s1 + s2;
    acc = acc * s1 + s2 * hv;
    m = nm;
  }
  const int col = head * D_ + ln;
  float outv = acc / den + gbias[col];
  spat[(size_t)(rbase + node) * H_ + col] = f2bf(outv > 0.f ? outv : 0.f);
}

// ---------------- 2-layer LSTM, persistent per-block (32 nodes), MFMA bf16 gates ----------------
// Numerics of this structure validated: R4 (this kernel) agreed bit-level with the
// fp32 VALU pipeline (R5/R6) through the bf16 output write.
__global__ __launch_bounds__(512, 2) void k_lstm(
    const u16* __restrict__ spat,
    const u16* __restrict__ Wih0, const u16* __restrict__ Whh0,
    const float* __restrict__ bih0, const float* __restrict__ bhh0,
    const u16* __restrict__ Wih1, const u16* __restrict__ Whh1,
    const float* __restrict__ bih1, const float* __restrict__ bhh1,
    float* __restrict__ h1f)
{
  __shared__ float gbuf[16 * GPAD];            // 33 KB: gate exchange, 16 nodes/pass
  __shared__ __align__(16) u16 h0s[32 * HPAD]; // 8.5 KB, pad 136 -> <=2-way LDS aliasing
  __shared__ __align__(16) u16 h1s[32 * HPAD];

  const int tid  = threadIdx.x;
  const int wave = tid >> 6;
  const int lane = tid & 63;
  const int l15  = lane & 15;
  const int quad = lane >> 4;
  const int n0   = blockIdx.x * 32;

  for(int i = tid; i < 32 * HPAD; i += 512){ h0s[i] = 0; h1s[i] = 0; }
  float cst[16];
  #pragma unroll
  for(int i = 0; i < 16; i++) cst[i] = 0.f;

  float bias[2][4];
  #pragma unroll
  for(int nt = 0; nt < 4; nt++){
    const int col = wave * 64 + nt * 16 + l15;
    bias[0][nt] = bih0[col] + bhh0[col];
    bias[1][nt] = bih1[col] + bhh1[col];
  }
  __syncthreads();

  #pragma unroll 1
  for(int t = 0; t < T_; t++){
    const u16* xrow = spat + (size_t)t * NTOT * H_;
    #pragma unroll
    for(int layer = 0; layer < 2; layer++){
      const u16* Wih = layer ? Wih1 : Wih0;
      const u16* Whh = layer ? Whh1 : Whh0;
      const u16* hprev = layer ? h1s : h0s;
      f32x4 acc[2][4];
      #pragma unroll
      for(int nt = 0; nt < 4; nt++){
        const float bv = bias[layer][nt];
        f32x4 b4 = {bv, bv, bv, bv};
        acc[0][nt] = b4; acc[1][nt] = b4;
      }
      #pragma unroll
      for(int ks = 0; ks < 4; ks++){
        const int k = ks * 32 + quad * 8;  // A[m=lane&15][k=quad*8+j]
        bf16x8 a1[2], a2[2], b1[4], b2[4];
        #pragma unroll
        for(int mt = 0; mt < 2; mt++){
          if(layer == 0)
            a1[mt] = *(const bf16x8*)(xrow + (size_t)(n0 + mt * 16 + l15) * H_ + k);
          else
            a1[mt] = *(const bf16x8*)(h0s + (mt * 16 + l15) * HPAD + k);
          a2[mt] = *(const bf16x8*)(hprev + (mt * 16 + l15) * HPAD + k);
        }
        #pragma unroll
        for(int nt = 0; nt < 4; nt++){
          const int col = wave * 64 + nt * 16 + l15;   // B[k][n=lane&15]
          b1[nt] = *(const bf16x8*)(Wih + col * H_ + k);
          b2[nt] = *(const bf16x8*)(Whh + col * H_ + k);
        }
        #pragma unroll
        for(int mt = 0; mt < 2; mt++){
          #pragma unroll
          for(int nt = 0; nt < 4; nt++){
            acc[mt][nt] = __builtin_amdgcn_mfma_f32_16x16x32_bf16(a1[mt], b1[nt], acc[mt][nt], 0, 0, 0);
            acc[mt][nt] = __builtin_amdgcn_mfma_f32_16x16x32_bf16(a2[mt], b2[nt], acc[mt][nt], 0, 0, 0);
          }
        }
      }
      u16* hcur = layer ? h1s : h0s;
      #pragma unroll
      for(int half = 0; half < 2; half++){
        // C/D layout: row = quad*4 + r, col = lane&15
        #pragma unroll
        for(int nt = 0; nt < 4; nt++){
          const int colL = wave * 64 + nt * 16 + l15;
          #pragma unroll
          for(int r = 0; r < 4; r++)
            gbuf[(quad * 4 + r) * GPAD + colL] = acc[half][nt][r];
        }
        __syncthreads();
        #pragma unroll
        for(int p = 0; p < 4; p++){
          const int il = p * 512 + tid;     // 16 nodes x 128 dims = 2048 items
          const int nl = il >> 7;
          const int dim = il & 127;
          const float gi = gbuf[nl * GPAD + dim];
          const float gf = gbuf[nl * GPAD + 128 + dim];
          const float gg = gbuf[nl * GPAD + 256 + dim];
          const float go = gbuf[nl * GPAD + 384 + dim];
          const int ci = layer * 8 + half * 4 + p;
          float c = sigf(gf) * cst[ci] + sigf(gi) * tanhfast(gg);
          cst[ci] = c;
          const float hv = sigf(go) * tanhfast(c);
          hcur[(half * 16 + nl) * HPAD + dim] = f2bf(hv);
          if(layer == 1 && t == T_ - 1)
            h1f[(size_t)(n0 + half * 16 + nl) * H_ + dim] = hv;
        }
        __syncthreads();
      }
    }
  }
}

// ---------------- LayerNorm: one wave per node, shuffle-only, fp32 output ----------------
__global__ __launch_bounds__(64) void k_ln(const float* __restrict__ h1f,
    const float* __restrict__ g, const float* __restrict__ b, float* __restrict__ out){
  const int node = blockIdx.x;
  const int tid = threadIdx.x;
  const float v0 = h1f[(size_t)node * H_ + tid];
  const float v1 = h1f[(size_t)node * H_ + 64 + tid];
  float s = v0 + v1;
  #pragma unroll
  for(int m = 32; m >= 1; m >>= 1) s += __shfl_xor(s, m);
  const float mu = s * (1.f / H_);
  const float d0 = v0 - mu, d1 = v1 - mu;
  s = d0 * d0 + d1 * d1;
  #pragma unroll
  for(int m = 32; m >= 1; m >>= 1) s += __shfl_xor(s, m);
  const float rstd = rsqrtf(s * (1.f / H_) + 1e-5f);
  out[(size_t)node * H_ + tid]      = d0 * rstd * g[tid]      + b[tid];
  out[(size_t)node * H_ + 64 + tid] = d1 * rstd * g[64 + tid] + b[64 + tid];
}

extern "C" void kernel_launch(void* const* d_in, const int* in_sizes, int n_in,
                              void* d_out, int out_size, void* d_ws, size_t ws_size,
                              hipStream_t stream) {
  (void)in_sizes; (void)n_in; (void)out_size; (void)ws_size;
  const float* x     = (const float*)d_in[0];
  const float* W     = (const float*)d_in[1];
  const float* att_s = (const float*)d_in[2];
  const float* att_d = (const float*)d_in[3];
  const float* gbias = (const float*)d_in[4];
  const float* Wih0  = (const float*)d_in[5];
  const float* Whh0  = (const float*)d_in[6];
  const float* bih0  = (const float*)d_in[7];
  const float* bhh0  = (const float*)d_in[8];
  const float* Wih1  = (const float*)d_in[9];
  const float* Whh1  = (const float*)d_in[10];
  const float* bih1  = (const float*)d_in[11];
  const float* bhh1  = (const float*)d_in[12];
  const float* lng   = (const float*)d_in[13];
  const float* lnb   = (const float*)d_in[14];
  const int*   ei    = (const int*)d_in[15];
  float* out = (float*)d_out;

  char* p = (char*)d_ws;
  auto carve = [&](size_t bytes) -> void* {
    void* r = (void*)p;
    p += (bytes + 255) & ~(size_t)255;
    return r;
  };
  u16* Wb_ih0 = (u16*)carve(512 * 128 * 2);
  u16* Wb_hh0 = (u16*)carve(512 * 128 * 2);
  u16* Wb_ih1 = (u16*)carve(512 * 128 * 2);
  u16* Wb_hh1 = (u16*)carve(512 * 128 * 2);
  float* hbuf  = (float*)carve((size_t)T_ * NTOT * H_ * 4);        // 41.9 MB
  float* asrc  = (float*)carve((size_t)T_ * NTOT * NHEADS * 4);
  float* adst  = (float*)carve((size_t)T_ * NTOT * NHEADS * 4);
  float* h1f   = (float*)carve((size_t)NTOT * H_ * 4);
  u16*   spat  = (u16*)carve((size_t)T_ * NTOT * H_ * 2);          // 21 MB
  int*   cnt   = (int*)carve(NTOT * 4);
  int*   curs  = (int*)carve(NTOT * 4);
  int*   rowst = (int*)carve((NTOT + 1) * 4);
  int*   csr   = (int*)carve((size_t)E_ * 4);

  hipLaunchKernelGGL(k_init,  dim3(32),    dim3(256),  0, stream, cnt);
  hipLaunchKernelGGL(k_count, dim3(256),   dim3(256),  0, stream, ei, cnt);
  hipLaunchKernelGGL(k_scan,  dim3(1),     dim3(1024), 0, stream, cnt, rowst, curs);
  hipLaunchKernelGGL(k_fill,  dim3(256),   dim3(256),  0, stream, ei, rowst, curs, csr);
  hipLaunchKernelGGL(k_wbf,   dim3(256),   dim3(256),  0, stream, Wih0, Wb_ih0);
  hipLaunchKernelGGL(k_wbf,   dim3(256),   dim3(256),  0, stream, Whh0, Wb_hh0);
  hipLaunchKernelGGL(k_wbf,   dim3(256),   dim3(256),  0, stream, Wih1, Wb_ih1);
  hipLaunchKernelGGL(k_wbf,   dim3(256),   dim3(256),  0, stream, Whh1, Wb_hh1);
  hipLaunchKernelGGL(k_proj,  dim3(10240), dim3(128),  0, stream, x, W, att_s, att_d, hbuf, asrc, adst);
  hipLaunchKernelGGL(k_edge,  dim3(40960), dim3(256),  0, stream, hbuf, asrc, adst, rowst, csr, gbias, spat);
  hipLaunchKernelGGL(k_lstm,  dim3(256),   dim3(512),  0, stream, spat,
                     Wb_ih0, Wb_hh0, bih0, bhh0, Wb_ih1, Wb_hh1, bih1, bhh1, h1f);
  hipLaunchKernelGGL(k_ln,    dim3(8192),  dim3(64),   0, stream, h1f, lng, lnb, out);
}

// Round 9
// 511.583 us; speedup vs baseline: 2.5820x; 1.0565x over previous
//
#include <hip/hip_runtime.h>

#define T_ 10
#define B_ 4
#define N_ 2048
#define NTOT 8192
#define F_ 64
#define H_ 128
#define NHEADS 4
#define D_ 32
#define E_ 65536
#define HPAD 136

typedef __bf16 bf16x8 __attribute__((ext_vector_type(8)));
typedef float f32x4 __attribute__((ext_vector_type(4)));
typedef unsigned short u16;

__device__ __forceinline__ float bf2f(u16 u){
  union { unsigned int i; float f; } v; v.i = ((unsigned int)u) << 16; return v.f;
}
__device__ __forceinline__ u16 f2bf(float f){
  union { float f; unsigned int i; } v; v.f = f;
  return (u16)((v.i + 0x7FFFu + ((v.i >> 16) & 1u)) >> 16);
}
__device__ __forceinline__ float sigf(float x){ return 1.f / (1.f + __expf(-x)); }
__device__ __forceinline__ float tanhfast(float x){ return 1.f - 2.f / (__expf(2.f * x) + 1.f); }

// ---------------- CSR build ----------------
__global__ __launch_bounds__(256) void k_init(int* __restrict__ cnt){
  int i = blockIdx.x * 256 + threadIdx.x;
  if(i < NTOT) cnt[i] = 0;
}

__global__ __launch_bounds__(256) void k_count(const int* __restrict__ ei, int* __restrict__ cnt){
  int e = blockIdx.x * 256 + threadIdx.x;
  if(e < E_) atomicAdd(&cnt[ei[E_ + e]], 1);
}

__global__ __launch_bounds__(1024) void k_scan(const int* __restrict__ cnt,
                                               int* __restrict__ rowst,
                                               int* __restrict__ cursor){
  __shared__ int lds[1024];
  const int t = threadIdx.x;
  int loc[8];
  int s = 0;
  #pragma unroll
  for(int i = 0; i < 8; i++){ loc[i] = s; s += cnt[t * 8 + i]; }
  lds[t] = s;
  __syncthreads();
  for(int off = 1; off < 1024; off <<= 1){
    int v = lds[t];
    int a = (t >= off) ? lds[t - off] : 0;
    __syncthreads();
    lds[t] = v + a;
    __syncthreads();
  }
  const int base = (t > 0) ? lds[t - 1] : 0;
  #pragma unroll
  for(int i = 0; i < 8; i++){
    rowst[t * 8 + i] = base + loc[i];
    cursor[t * 8 + i] = 0;
  }
  if(t == 1023) rowst[NTOT] = lds[1023];
}

__global__ __launch_bounds__(256) void k_fill(const int* __restrict__ ei,
                                              const int* __restrict__ rowst,
                                              int* __restrict__ cursor,
                                              int* __restrict__ csr){
  int e = blockIdx.x * 256 + threadIdx.x;
  if(e < E_){
    int d = ei[E_ + e];
    int pos = atomicAdd(&cursor[d], 1);
    csr[rowst[d] + pos] = ei[e];
  }
}

// ---- gate-permuted fp32->bf16 weight conversion: row p=(d>>4)*64+g*16+(d&15) <- row g*128+d
__global__ __launch_bounds__(256) void k_wperm(const float* __restrict__ src, u16* __restrict__ dst){
  int i = blockIdx.x * 256 + threadIdx.x;
  if(i < 512 * 128){
    int p = i >> 7, k = i & 127;
    int w = p >> 6, g = (p >> 4) & 3, l = p & 15;
    int row = g * 128 + w * 16 + l;
    dst[i] = f2bf(src[row * 128 + k]);
  }
}

// ---------------- GAT projection + attention coefficients (fp32 math, bf16 hbuf out) ----------------
__global__ __launch_bounds__(128) void k_proj(const float* __restrict__ x,
    const float* __restrict__ W, const float* __restrict__ att_s, const float* __restrict__ att_d,
    u16* __restrict__ hbuf, float* __restrict__ asrc, float* __restrict__ adst){
  __shared__ float Wl[F_ * H_];
  __shared__ float xl[8 * F_];
  const int tid = threadIdx.x;
  for(int i = tid; i < F_ * H_; i += 128) Wl[i] = W[i];
  const int r0 = blockIdx.x * 8;
  for(int i = tid; i < 8 * F_; i += 128){
    const int r = i >> 6, f = i & 63;
    const int row = r0 + r;
    const int t = row >> 13, nt = row & 8191;
    const int bb = nt >> 11, n = nt & 2047;
    xl[i] = x[(((size_t)bb * T_ + t) * N_ + n) * F_ + f];
  }
  __syncthreads();
  const int col = tid;  // 0..127
  const float wsv = att_s[col];
  const float wdv = att_d[col];
  for(int r = 0; r < 8; r++){
    float acc = 0.f;
    #pragma unroll
    for(int k = 0; k < F_; k++) acc += xl[r * F_ + k] * Wl[k * H_ + col];
    const int row = r0 + r;
    hbuf[(size_t)row * H_ + col] = f2bf(acc);
    float vs = acc * wsv, vd = acc * wdv;
    #pragma unroll
    for(int m = 16; m >= 1; m >>= 1){ vs += __shfl_xor(vs, m); vd += __shfl_xor(vd, m); }
    if((tid & 31) == 0){
      const int head = col >> 5;
      asrc[(size_t)row * NHEADS + head] = vs;
      adst[(size_t)row * NHEADS + head] = vd;
    }
  }
}

// ---------------- GAT edge softmax + aggregation (gather, online softmax) -> bf16 spat ----------------
__global__ __launch_bounds__(256) void k_edge(const u16* __restrict__ hbuf,
    const float* __restrict__ asrc, const float* __restrict__ adst,
    const int* __restrict__ rowst, const int* __restrict__ csr,
    const float* __restrict__ gbias, u16* __restrict__ spat){
  const int g = blockIdx.x * 256 + threadIdx.x;
  const int task = g >> 5;
  const int ln = g & 31;
  const int head = task & 3;
  const int node = (task >> 2) & 8191;
  const int t = task >> 15;
  const int rbase = t * NTOT;
  const float ad = adst[(size_t)(rbase + node) * NHEADS + head];
  // self-loop first (reference concatenates self-loops)
  float e = asrc[(size_t)(rbase + node) * NHEADS + head] + ad;
  e = e > 0.f ? e : 0.2f * e;
  float m = e, den = 1.f;
  float acc = bf2f(hbuf[(size_t)(rbase + node) * H_ + head * D_ + ln]);
  const int rs = rowst[node], re = rowst[node + 1];
  for(int i = rs; i < re; i++){
    const int s = csr[i];
    float ev = asrc[(size_t)(rbase + s) * NHEADS + head] + ad;
    ev = ev > 0.f ? ev : 0.2f * ev;
    const float hv = bf2f(hbuf[(size_t)(rbase + s) * H_ + head * D_ + ln]);
    const float nm = fmaxf(m, ev);
    const float s1 = __expf(m - nm), s2 = __expf(ev - nm);
    den = den * s1 + s2;
    acc = acc * s1 + s2 * hv;
    m = nm;
  }
  const int col = head * D_ + ln;
  float outv = acc / den + gbias[col];
  spat[(size_t)(rbase + node) * H_ + col] = f2bf(outv > 0.f ? outv : 0.f);
}

// ---------------- 2-layer LSTM: gate-permuted MFMA, in-register epilogue ----------------
// Wave w's nt-tile = gate nt of dim d = w*16 + (lane&15); lane holds all 4 gates of
// (node, d) in acc[mt][0..3][r] -> LSTM nonlinearity entirely in registers.
// Double-buffered h in LDS; 2 barriers per timestep.
__global__ __launch_bounds__(512, 1) void k_lstm(
    const u16* __restrict__ spat,
    const u16* __restrict__ Wp_ih0, const u16* __restrict__ Wp_hh0,
    const float* __restrict__ bih0, const float* __restrict__ bhh0,
    const u16* __restrict__ Wp_ih1, const u16* __restrict__ Wp_hh1,
    const float* __restrict__ bih1, const float* __restrict__ bhh1,
    float* __restrict__ h1f)
{
  __shared__ __align__(16) u16 h0s[2][32 * HPAD];  // 2 x 8.5 KB
  __shared__ __align__(16) u16 h1s[2][32 * HPAD];

  const int tid  = threadIdx.x;
  const int wave = tid >> 6;
  const int lane = tid & 63;
  const int l15  = lane & 15;
  const int quad = lane >> 4;
  const int n0   = blockIdx.x * 32;
  const int dim  = wave * 16 + l15;

  for(int i = tid; i < 2 * 32 * HPAD; i += 512){
    ((u16*)h0s)[i] = 0; ((u16*)h1s)[i] = 0;
  }
  float cst[16];
  #pragma unroll
  for(int i = 0; i < 16; i++) cst[i] = 0.f;

  float bias[2][4];
  #pragma unroll
  for(int g = 0; g < 4; g++){
    bias[0][g] = bih0[g * 128 + dim] + bhh0[g * 128 + dim];
    bias[1][g] = bih1[g * 128 + dim] + bhh1[g * 128 + dim];
  }
  __syncthreads();

  #pragma unroll 1
  for(int t = 0; t < T_; t++){
    const u16* xrow = spat + (size_t)t * NTOT * H_;
    const int rp = t & 1, wp = rp ^ 1;
    #pragma unroll
    for(int layer = 0; layer < 2; layer++){
      const u16* Wih = layer ? Wp_ih1 : Wp_ih0;
      const u16* Whh = layer ? Wp_hh1 : Wp_hh0;
      const u16* hpv = layer ? h1s[rp] : h0s[rp];
      f32x4 acc[2][4];
      #pragma unroll
      for(int nt = 0; nt < 4; nt++){
        const float bv = bias[layer][nt];
        f32x4 b4 = {bv, bv, bv, bv};
        acc[0][nt] = b4; acc[1][nt] = b4;
      }
      #pragma unroll
      for(int ks = 0; ks < 4; ks++){
        const int k = ks * 32 + quad * 8;  // A[m=lane&15][k=quad*8+j]
        bf16x8 a1[2], a2[2];
        #pragma unroll
        for(int mt = 0; mt < 2; mt++){
          if(layer == 0)
            a1[mt] = *(const bf16x8*)(xrow + (size_t)(n0 + mt * 16 + l15) * H_ + k);
          else
            a1[mt] = *(const bf16x8*)(h0s[wp] + (mt * 16 + l15) * HPAD + k);
          a2[mt] = *(const bf16x8*)(hpv + (mt * 16 + l15) * HPAD + k);
        }
        #pragma unroll
        for(int nt = 0; nt < 4; nt++){
          const int row = wave * 64 + nt * 16 + l15;   // permuted weight row
          const bf16x8 b1 = *(const bf16x8*)(Wih + row * H_ + k);
          const bf16x8 b2 = *(const bf16x8*)(Whh + row * H_ + k);
          #pragma unroll
          for(int mt = 0; mt < 2; mt++){
            acc[mt][nt] = __builtin_amdgcn_mfma_f32_16x16x32_bf16(a1[mt], b1, acc[mt][nt], 0, 0, 0);
            acc[mt][nt] = __builtin_amdgcn_mfma_f32_16x16x32_bf16(a2[mt], b2, acc[mt][nt], 0, 0, 0);
          }
        }
      }
      // in-register epilogue: C/D row = quad*4 + r (node), this lane's dim fixed
      u16* hcur = layer ? h1s[wp] : h0s[wp];
      #pragma unroll
      for(int mt = 0; mt < 2; mt++){
        #pragma unroll
        for(int r = 0; r < 4; r++){
          const int node = mt * 16 + quad * 4 + r;
          const float gi = acc[mt][0][r];
          const float gf = acc[mt][1][r];
          const float gg = acc[mt][2][r];
          const float go = acc[mt][3][r];
          const int ci = layer * 8 + mt * 4 + r;
          const float c = sigf(gf) * cst[ci] + sigf(gi) * tanhfast(gg);
          cst[ci] = c;
          const float hv = sigf(go) * tanhfast(c);
          hcur[node * HPAD + dim] = f2bf(hv);
          if(layer == 1 && t == T_ - 1)
            h1f[(size_t)(n0 + node) * H_ + dim] = hv;
        }
      }
      __syncthreads();
    }
  }
}

// ---------------- LayerNorm: one wave per node, shuffle-only, fp32 output ----------------
__global__ __launch_bounds__(64) void k_ln(const float* __restrict__ h1f,
    const float* __restrict__ g, const float* __restrict__ b, float* __restrict__ out){
  const int node = blockIdx.x;
  const int tid = threadIdx.x;
  const float v0 = h1f[(size_t)node * H_ + tid];
  const float v1 = h1f[(size_t)node * H_ + 64 + tid];
  float s = v0 + v1;
  #pragma unroll
  for(int m = 32; m >= 1; m >>= 1) s += __shfl_xor(s, m);
  const float mu = s * (1.f / H_);
  const float d0 = v0 - mu, d1 = v1 - mu;
  s = d0 * d0 + d1 * d1;
  #pragma unroll
  for(int m = 32; m >= 1; m >>= 1) s += __shfl_xor(s, m);
  const float rstd = rsqrtf(s * (1.f / H_) + 1e-5f);
  out[(size_t)node * H_ + tid]      = d0 * rstd * g[tid]      + b[tid];
  out[(size_t)node * H_ + 64 + tid] = d1 * rstd * g[64 + tid] + b[64 + tid];
}

extern "C" void kernel_launch(void* const* d_in, const int* in_sizes, int n_in,
                              void* d_out, int out_size, void* d_ws, size_t ws_size,
                              hipStream_t stream) {
  (void)in_sizes; (void)n_in; (void)out_size; (void)ws_size;
  const float* x     = (const float*)d_in[0];
  const float* W     = (const float*)d_in[1];
  const float* att_s = (const float*)d_in[2];
  const float* att_d = (const float*)d_in[3];
  const float* gbias = (const float*)d_in[4];
  const float* Wih0  = (const float*)d_in[5];
  const float* Whh0  = (const float*)d_in[6];
  const float* bih0  = (const float*)d_in[7];
  const float* bhh0  = (const float*)d_in[8];
  const float* Wih1  = (const float*)d_in[9];
  const float* Whh1  = (const float*)d_in[10];
  const float* bih1  = (const float*)d_in[11];
  const float* bhh1  = (const float*)d_in[12];
  const float* lng   = (const float*)d_in[13];
  const float* lnb   = (const float*)d_in[14];
  const int*   ei    = (const int*)d_in[15];
  float* out = (float*)d_out;

  char* p = (char*)d_ws;
  auto carve = [&](size_t bytes) -> void* {
    void* r = (void*)p;
    p += (bytes + 255) & ~(size_t)255;
    return r;
  };
  u16* Wp_ih0 = (u16*)carve(512 * 128 * 2);
  u16* Wp_hh0 = (u16*)carve(512 * 128 * 2);
  u16* Wp_ih1 = (u16*)carve(512 * 128 * 2);
  u16* Wp_hh1 = (u16*)carve(512 * 128 * 2);
  u16*   hbuf  = (u16*)carve((size_t)T_ * NTOT * H_ * 2);          // 21 MB bf16
  float* asrc  = (float*)carve((size_t)T_ * NTOT * NHEADS * 4);
  float* adst  = (float*)carve((size_t)T_ * NTOT * NHEADS * 4);
  float* h1f   = (float*)carve((size_t)NTOT * H_ * 4);
  u16*   spat  = (u16*)carve((size_t)T_ * NTOT * H_ * 2);          // 21 MB bf16
  int*   cnt   = (int*)carve(NTOT * 4);
  int*   curs  = (int*)carve(NTOT * 4);
  int*   rowst = (int*)carve((NTOT + 1) * 4);
  int*   csr   = (int*)carve((size_t)E_ * 4);

  hipLaunchKernelGGL(k_init,  dim3(32),    dim3(256),  0, stream, cnt);
  hipLaunchKernelGGL(k_count, dim3(256),   dim3(256),  0, stream, ei, cnt);
  hipLaunchKernelGGL(k_scan,  dim3(1),     dim3(1024), 0, stream, cnt, rowst, curs);
  hipLaunchKernelGGL(k_fill,  dim3(256),   dim3(256),  0, stream, ei, rowst, curs, csr);
  hipLaunchKernelGGL(k_wperm, dim3(256),   dim3(256),  0, stream, Wih0, Wp_ih0);
  hipLaunchKernelGGL(k_wperm, dim3(256),   dim3(256),  0, stream, Whh0, Wp_hh0);
  hipLaunchKernelGGL(k_wperm, dim3(256),   dim3(256),  0, stream, Wih1, Wp_ih1);
  hipLaunchKernelGGL(k_wperm, dim3(256),   dim3(256),  0, stream, Whh1, Wp_hh1);
  hipLaunchKernelGGL(k_proj,  dim3(10240), dim3(128),  0, stream, x, W, att_s, att_d, hbuf, asrc, adst);
  hipLaunchKernelGGL(k_edge,  dim3(40960), dim3(256),  0, stream, hbuf, asrc, adst, rowst, csr, gbias, spat);
  hipLaunchKernelGGL(k_lstm,  dim3(256),   dim3(512),  0, stream, spat,
                     Wp_ih0, Wp_hh0, bih0, bhh0, Wp_ih1, Wp_hh1, bih1, bhh1, h1f);
  hipLaunchKernelGGL(k_ln,    dim3(8192),  dim3(64),   0, stream, h1f, lng, lnb, out);
}

// Round 10
// 447.230 us; speedup vs baseline: 2.9535x; 1.1439x over previous
//
#include <hip/hip_runtime.h>

#define T_ 10
#define B_ 4
#define N_ 2048
#define NTOT 8192
#define F_ 64
#define H_ 128
#define NHEADS 4
#define D_ 32
#define E_ 65536
#define HPAD 136

typedef __bf16 bf16x8 __attribute__((ext_vector_type(8)));
typedef float f32x4 __attribute__((ext_vector_type(4)));
typedef unsigned short u16;

__device__ __forceinline__ float bf2f(u16 u){
  union { unsigned int i; float f; } v; v.i = ((unsigned int)u) << 16; return v.f;
}
__device__ __forceinline__ u16 f2bf(float f){
  union { float f; unsigned int i; } v; v.f = f;
  return (u16)((v.i + 0x7FFFu + ((v.i >> 16) & 1u)) >> 16);
}
__device__ __forceinline__ float sigf(float x){ return 1.f / (1.f + __expf(-x)); }
__device__ __forceinline__ float tanhfast(float x){ return 1.f - 2.f / (__expf(2.f * x) + 1.f); }

// ---------------- CSR build ----------------
__global__ __launch_bounds__(256) void k_init(int* __restrict__ cnt){
  int i = blockIdx.x * 256 + threadIdx.x;
  if(i < NTOT) cnt[i] = 0;
}

__global__ __launch_bounds__(256) void k_count(const int* __restrict__ ei, int* __restrict__ cnt){
  int e = blockIdx.x * 256 + threadIdx.x;
  if(e < E_) atomicAdd(&cnt[ei[E_ + e]], 1);
}

__global__ __launch_bounds__(1024) void k_scan(const int* __restrict__ cnt,
                                               int* __restrict__ rowst,
                                               int* __restrict__ cursor){
  __shared__ int lds[1024];
  const int t = threadIdx.x;
  int loc[8];
  int s = 0;
  #pragma unroll
  for(int i = 0; i < 8; i++){ loc[i] = s; s += cnt[t * 8 + i]; }
  lds[t] = s;
  __syncthreads();
  for(int off = 1; off < 1024; off <<= 1){
    int v = lds[t];
    int a = (t >= off) ? lds[t - off] : 0;
    __syncthreads();
    lds[t] = v + a;
    __syncthreads();
  }
  const int base = (t > 0) ? lds[t - 1] : 0;
  #pragma unroll
  for(int i = 0; i < 8; i++){
    rowst[t * 8 + i] = base + loc[i];
    cursor[t * 8 + i] = 0;
  }
  if(t == 1023) rowst[NTOT] = lds[1023];
}

__global__ __launch_bounds__(256) void k_fill(const int* __restrict__ ei,
                                              const int* __restrict__ rowst,
                                              int* __restrict__ cursor,
                                              int* __restrict__ csr){
  int e = blockIdx.x * 256 + threadIdx.x;
  if(e < E_){
    int d = ei[E_ + e];
    int pos = atomicAdd(&cursor[d], 1);
    csr[rowst[d] + pos] = ei[e];
  }
}

// ---- gate-permuted fp32->bf16 LSTM weights (4 matrices via blockIdx.y) ----
__global__ __launch_bounds__(256) void k_wperm(const float* __restrict__ s0, u16* __restrict__ d0,
                                               const float* __restrict__ s1, u16* __restrict__ d1,
                                               const float* __restrict__ s2, u16* __restrict__ d2,
                                               const float* __restrict__ s3, u16* __restrict__ d3){
  const float* src = blockIdx.y == 0 ? s0 : blockIdx.y == 1 ? s1 : blockIdx.y == 2 ? s2 : s3;
  u16* dst = blockIdx.y == 0 ? d0 : blockIdx.y == 1 ? d1 : blockIdx.y == 2 ? d2 : d3;
  int i = blockIdx.x * 256 + threadIdx.x;
  if(i < 512 * 128){
    int p = i >> 7, k = i & 127;
    int w = p >> 6, g = (p >> 4) & 3, l = p & 15;
    int row = g * 128 + w * 16 + l;
    dst[i] = f2bf(src[row * 128 + k]);
  }
}

// ---- GAT W (F x H fp32) -> W^T (H x F bf16) for MFMA B-fragments ----
__global__ __launch_bounds__(256) void k_wtc(const float* __restrict__ W, u16* __restrict__ Wt){
  int i = blockIdx.x * 256 + threadIdx.x;   // i over H*F
  if(i < H_ * F_){
    int nn = i >> 6, f = i & 63;
    Wt[i] = f2bf(W[f * H_ + nn]);
  }
}

// ---------------- MFMA GAT projection + attention coefficients ----------------
// Wave = 16 rows x 128 cols. A: x rows (fp32->bf16 inline). B: Wt[col][f] contiguous-k.
// C layout: row = quad*4+r, col = nt*16+l15 (same convention HW-validated in k_lstm).
__global__ __launch_bounds__(256) void k_projm(const float* __restrict__ x,
    const u16* __restrict__ Wt, const float* __restrict__ att_s, const float* __restrict__ att_d,
    u16* __restrict__ hbuf, float* __restrict__ asrc, float* __restrict__ adst){
  const int tid  = threadIdx.x;
  const int wave = tid >> 6;
  const int lane = tid & 63;
  const int l15  = lane & 15;
  const int quad = lane >> 4;
  const int r0   = blockIdx.x * 64 + wave * 16;
  const int row  = r0 + l15;
  const int t = row >> 13, nt = row & 8191;
  const int b = nt >> 11, n = nt & 2047;
  const float* xrow = x + (((size_t)b * T_ + t) * N_ + n) * F_;

  bf16x8 a[2];
  #pragma unroll
  for(int ks = 0; ks < 2; ks++){
    const float4 f0 = *(const float4*)(xrow + ks * 32 + quad * 8);
    const float4 f1 = *(const float4*)(xrow + ks * 32 + quad * 8 + 4);
    bf16x8 av;
    av[0] = (__bf16)f0.x; av[1] = (__bf16)f0.y; av[2] = (__bf16)f0.z; av[3] = (__bf16)f0.w;
    av[4] = (__bf16)f1.x; av[5] = (__bf16)f1.y; av[6] = (__bf16)f1.z; av[7] = (__bf16)f1.w;
    a[ks] = av;
  }

  f32x4 acc[8];
  #pragma unroll
  for(int c = 0; c < 8; c++){ f32x4 z = {0.f,0.f,0.f,0.f}; acc[c] = z; }
  #pragma unroll
  for(int c = 0; c < 8; c++){
    #pragma unroll
    for(int ks = 0; ks < 2; ks++){
      const bf16x8 bv = *(const bf16x8*)(Wt + (c * 16 + l15) * F_ + ks * 32 + quad * 8);
      acc[c] = __builtin_amdgcn_mfma_f32_16x16x32_bf16(a[ks], bv, acc[c], 0, 0, 0);
    }
  }

  // att coefficient partials + hbuf write
  float ps[4][4], pd[4][4];   // [r][head]
  #pragma unroll
  for(int r = 0; r < 4; r++)
    #pragma unroll
    for(int h = 0; h < 4; h++){ ps[r][h] = 0.f; pd[r][h] = 0.f; }

  #pragma unroll
  for(int c = 0; c < 8; c++){
    const int col = c * 16 + l15;
    const float asv = att_s[col];
    const float adv = att_d[col];
    const int head = c >> 1;
    #pragma unroll
    for(int r = 0; r < 4; r++){
      const float v = acc[c][r];
      hbuf[(size_t)(r0 + quad * 4 + r) * H_ + col] = f2bf(v);
      ps[r][head] += v * asv;
      pd[r][head] += v * adv;
    }
  }
  // reduce over l15 (16-lane groups; masks < 16 stay in group)
  #pragma unroll
  for(int m = 8; m >= 1; m >>= 1){
    #pragma unroll
    for(int r = 0; r < 4; r++)
      #pragma unroll
      for(int h = 0; h < 4; h++){
        ps[r][h] += __shfl_xor(ps[r][h], m);
        pd[r][h] += __shfl_xor(pd[r][h], m);
      }
  }
  if(l15 == 0){
    #pragma unroll
    for(int r = 0; r < 4; r++){
      const int rw = r0 + quad * 4 + r;
      #pragma unroll
      for(int h = 0; h < 4; h++){
        asrc[(size_t)rw * NHEADS + h] = ps[r][h];
        adst[(size_t)rw * NHEADS + h] = pd[r][h];
      }
    }
  }
}

// ---------------- GAT edge softmax + aggregation (gather, online softmax) -> bf16 spat ----------------
__global__ __launch_bounds__(256) void k_edge(const u16* __restrict__ hbuf,
    const float* __restrict__ asrc, const float* __restrict__ adst,
    const int* __restrict__ rowst, const int* __restrict__ csr,
    const float* __restrict__ gbias, u16* __restrict__ spat){
  const int g = blockIdx.x * 256 + threadIdx.x;
  const int task = g >> 5;
  const int ln = g & 31;
  const int head = task & 3;
  const int node = (task >> 2) & 8191;
  const int t = task >> 15;
  const int rbase = t * NTOT;
  const float ad = adst[(size_t)(rbase + node) * NHEADS + head];
  // self-loop first (reference concatenates self-loops)
  float e = asrc[(size_t)(rbase + node) * NHEADS + head] + ad;
  e = e > 0.f ? e : 0.2f * e;
  float m = e, den = 1.f;
  float acc = bf2f(hbuf[(size_t)(rbase + node) * H_ + head * D_ + ln]);
  const int rs = rowst[node], re = rowst[node + 1];
  for(int i = rs; i < re; i++){
    const int s = csr[i];
    float ev = asrc[(size_t)(rbase + s) * NHEADS + head] + ad;
    ev = ev > 0.f ? ev : 0.2f * ev;
    const float hv = bf2f(hbuf[(size_t)(rbase + s) * H_ + head * D_ + ln]);
    const float nm = fmaxf(m, ev);
    const float s1 = __expf(m - nm), s2 = __expf(ev - nm);
    den = den * s1 + s2;
    acc = acc * s1 + s2 * hv;
    m = nm;
  }
  const int col = head * D_ + ln;
  float outv = acc / den + gbias[col];
  spat[(size_t)(rbase + node) * H_ + col] = f2bf(outv > 0.f ? outv : 0.f);
}

// ---------------- 2-layer LSTM: gate-permuted MFMA, in-register epilogue ----------------
// 32 nodes/block, 256 blocks. __launch_bounds__(512,2): VGPR cap 256 -> no scratch spill
// (live set ~95 regs); occupancy 1 block/CU, same as measured before, minus the spill traffic.
__global__ __launch_bounds__(512, 2) void k_lstm(
    const u16* __restrict__ spat,
    const u16* __restrict__ Wp_ih0, const u16* __restrict__ Wp_hh0,
    const float* __restrict__ bih0, const float* __restrict__ bhh0,
    const u16* __restrict__ Wp_ih1, const u16* __restrict__ Wp_hh1,
    const float* __restrict__ bih1, const float* __restrict__ bhh1,
    float* __restrict__ h1f)
{
  __shared__ __align__(16) u16 h0s[2][32 * HPAD];  // 2 x 8.5 KB
  __shared__ __align__(16) u16 h1s[2][32 * HPAD];

  const int tid  = threadIdx.x;
  const int wave = tid >> 6;
  const int lane = tid & 63;
  const int l15  = lane & 15;
  const int quad = lane >> 4;
  const int n0   = blockIdx.x * 32;
  const int dim  = wave * 16 + l15;

  for(int i = tid; i < 2 * 32 * HPAD; i += 512){
    ((u16*)h0s)[i] = 0; ((u16*)h1s)[i] = 0;
  }
  float cst[16];
  #pragma unroll
  for(int i = 0; i < 16; i++) cst[i] = 0.f;

  float bias[2][4];
  #pragma unroll
  for(int g = 0; g < 4; g++){
    bias[0][g] = bih0[g * 128 + dim] + bhh0[g * 128 + dim];
    bias[1][g] = bih1[g * 128 + dim] + bhh1[g * 128 + dim];
  }
  __syncthreads();

  #pragma unroll 1
  for(int t = 0; t < T_; t++){
    const u16* xrow = spat + (size_t)t * NTOT * H_;
    const int rp = t & 1, wp = rp ^ 1;
    #pragma unroll
    for(int layer = 0; layer < 2; layer++){
      const u16* Wih = layer ? Wp_ih1 : Wp_ih0;
      const u16* Whh = layer ? Wp_hh1 : Wp_hh0;
      const u16* hpv = layer ? h1s[rp] : h0s[rp];
      f32x4 acc[2][4];
      #pragma unroll
      for(int nt = 0; nt < 4; nt++){
        const float bv = bias[layer][nt];
        f32x4 b4 = {bv, bv, bv, bv};
        acc[0][nt] = b4; acc[1][nt] = b4;
      }
      #pragma unroll
      for(int ks = 0; ks < 4; ks++){
        const int k = ks * 32 + quad * 8;  // A[m=lane&15][k=quad*8+j]
        bf16x8 a1[2], a2[2];
        #pragma unroll
        for(int mt = 0; mt < 2; mt++){
          if(layer == 0)
            a1[mt] = *(const bf16x8*)(xrow + (size_t)(n0 + mt * 16 + l15) * H_ + k);
          else
            a1[mt] = *(const bf16x8*)(h0s[wp] + (mt * 16 + l15) * HPAD + k);
          a2[mt] = *(const bf16x8*)(hpv + (mt * 16 + l15) * HPAD + k);
        }
        #pragma unroll
        for(int nt = 0; nt < 4; nt++){
          const int row = wave * 64 + nt * 16 + l15;   // permuted weight row
          const bf16x8 b1 = *(const bf16x8*)(Wih + row * H_ + k);
          const bf16x8 b2 = *(const bf16x8*)(Whh + row * H_ + k);
          #pragma unroll
          for(int mt = 0; mt < 2; mt++){
            acc[mt][nt] = __builtin_amdgcn_mfma_f32_16x16x32_bf16(a1[mt], b1, acc[mt][nt], 0, 0, 0);
            acc[mt][nt] = __builtin_amdgcn_mfma_f32_16x16x32_bf16(a2[mt], b2, acc[mt][nt], 0, 0, 0);
          }
        }
      }
      // in-register epilogue: C/D row = quad*4 + r (node), this lane's dim fixed
      u16* hcur = layer ? h1s[wp] : h0s[wp];
      #pragma unroll
      for(int mt = 0; mt < 2; mt++){
        #pragma unroll
        for(int r = 0; r < 4; r++){
          const int node = mt * 16 + quad * 4 + r;
          const float gi = acc[mt][0][r];
          const float gf = acc[mt][1][r];
          const float gg = acc[mt][2][r];
          const float go = acc[mt][3][r];
          const int ci = layer * 8 + mt * 4 + r;
          const float c = sigf(gf) * cst[ci] + sigf(gi) * tanhfast(gg);
          cst[ci] = c;
          const float hv = sigf(go) * tanhfast(c);
          hcur[node * HPAD + dim] = f2bf(hv);
          if(layer == 1 && t == T_ - 1)
            h1f[(size_t)(n0 + node) * H_ + dim] = hv;
        }
      }
      __syncthreads();
    }
  }
}

// ---------------- LayerNorm: one wave per node, shuffle-only, fp32 output ----------------
__global__ __launch_bounds__(64) void k_ln(const float* __restrict__ h1f,
    const float* __restrict__ g, const float* __restrict__ b, float* __restrict__ out){
  const int node = blockIdx.x;
  const int tid = threadIdx.x;
  const float v0 = h1f[(size_t)node * H_ + tid];
  const float v1 = h1f[(size_t)node * H_ + 64 + tid];
  float s = v0 + v1;
  #pragma unroll
  for(int m = 32; m >= 1; m >>= 1) s += __shfl_xor(s, m);
  const float mu = s * (1.f / H_);
  const float d0 = v0 - mu, d1 = v1 - mu;
  s = d0 * d0 + d1 * d1;
  #pragma unroll
  for(int m = 32; m >= 1; m >>= 1) s += __shfl_xor(s, m);
  const float rstd = rsqrtf(s * (1.f / H_) + 1e-5f);
  out[(size_t)node * H_ + tid]      = d0 * rstd * g[tid]      + b[tid];
  out[(size_t)node * H_ + 64 + tid] = d1 * rstd * g[64 + tid] + b[64 + tid];
}

extern "C" void kernel_launch(void* const* d_in, const int* in_sizes, int n_in,
                              void* d_out, int out_size, void* d_ws, size_t ws_size,
                              hipStream_t stream) {
  (void)in_sizes; (void)n_in; (void)out_size; (void)ws_size;
  const float* x     = (const float*)d_in[0];
  const float* W     = (const float*)d_in[1];
  const float* att_s = (const float*)d_in[2];
  const float* att_d = (const float*)d_in[3];
  const float* gbias = (const float*)d_in[4];
  const float* Wih0  = (const float*)d_in[5];
  const float* Whh0  = (const float*)d_in[6];
  const float* bih0  = (const float*)d_in[7];
  const float* bhh0  = (const float*)d_in[8];
  const float* Wih1  = (const float*)d_in[9];
  const float* Whh1  = (const float*)d_in[10];
  const float* bih1  = (const float*)d_in[11];
  const float* bhh1  = (const float*)d_in[12];
  const float* lng   = (const float*)d_in[13];
  const float* lnb   = (const float*)d_in[14];
  const int*   ei    = (const int*)d_in[15];
  float* out = (float*)d_out;

  char* p = (char*)d_ws;
  auto carve = [&](size_t bytes) -> void* {
    void* r = (void*)p;
    p += (bytes + 255) & ~(size_t)255;
    return r;
  };
  u16* Wp_ih0 = (u16*)carve(512 * 128 * 2);
  u16* Wp_hh0 = (u16*)carve(512 * 128 * 2);
  u16* Wp_ih1 = (u16*)carve(512 * 128 * 2);
  u16* Wp_hh1 = (u16*)carve(512 * 128 * 2);
  u16* Wt     = (u16*)carve(H_ * F_ * 2);
  u16*   hbuf  = (u16*)carve((size_t)T_ * NTOT * H_ * 2);          // 21 MB bf16
  float* asrc  = (float*)carve((size_t)T_ * NTOT * NHEADS * 4);
  float* adst  = (float*)carve((size_t)T_ * NTOT * NHEADS * 4);
  float* h1f   = (float*)carve((size_t)NTOT * H_ * 4);
  u16*   spat  = (u16*)carve((size_t)T_ * NTOT * H_ * 2);          // 21 MB bf16
  int*   cnt   = (int*)carve(NTOT * 4);
  int*   curs  = (int*)carve(NTOT * 4);
  int*   rowst = (int*)carve((NTOT + 1) * 4);
  int*   csr   = (int*)carve((size_t)E_ * 4);

  hipLaunchKernelGGL(k_init,  dim3(32),         dim3(256),  0, stream, cnt);
  hipLaunchKernelGGL(k_count, dim3(256),        dim3(256),  0, stream, ei, cnt);
  hipLaunchKernelGGL(k_scan,  dim3(1),          dim3(1024), 0, stream, cnt, rowst, curs);
  hipLaunchKernelGGL(k_fill,  dim3(256),        dim3(256),  0, stream, ei, rowst, curs, csr);
  hipLaunchKernelGGL(k_wperm, dim3(256, 4),     dim3(256),  0, stream,
                     Wih0, Wp_ih0, Whh0, Wp_hh0, Wih1, Wp_ih1, Whh1, Wp_hh1);
  hipLaunchKernelGGL(k_wtc,   dim3(32),         dim3(256),  0, stream, W, Wt);
  hipLaunchKernelGGL(k_projm, dim3(1280),       dim3(256),  0, stream, x, Wt, att_s, att_d, hbuf, asrc, adst);
  hipLaunchKernelGGL(k_edge,  dim3(40960),      dim3(256),  0, stream, hbuf, asrc, adst, rowst, csr, gbias, spat);
  hipLaunchKernelGGL(k_lstm,  dim3(256),        dim3(512),  0, stream, spat,
                     Wp_ih0, Wp_hh0, bih0, bhh0, Wp_ih1, Wp_hh1, bih1, bhh1, h1f);
  hipLaunchKernelGGL(k_ln,    dim3(8192),       dim3(64),   0, stream, h1f, lng, lnb, out);
}

// Round 11
// 431.932 us; speedup vs baseline: 3.0581x; 1.0354x over previous
//
#include <hip/hip_runtime.h>

#define T_ 10
#define B_ 4
#define N_ 2048
#define NTOT 8192
#define F_ 64
#define H_ 128
#define NHEADS 4
#define D_ 32
#define E_ 65536
#define EF 73728          // E + NTOT self-loops
#define HPAD 136

typedef __bf16 bf16x8 __attribute__((ext_vector_type(8)));
typedef float f32x4 __attribute__((ext_vector_type(4)));
typedef unsigned short u16;

__device__ __forceinline__ float bf2f(u16 u){
  union { unsigned int i; float f; } v; v.i = ((unsigned int)u) << 16; return v.f;
}
__device__ __forceinline__ u16 f2bf(float f){
  union { float f; unsigned int i; } v; v.f = f;
  return (u16)((v.i + 0x7FFFu + ((v.i >> 16) & 1u)) >> 16);
}
__device__ __forceinline__ float sigf(float x){ return 1.f / (1.f + __expf(-x)); }
__device__ __forceinline__ float tanhfast(float x){ return 1.f - 2.f / (__expf(2.f * x) + 1.f); }
__device__ __forceinline__ float lrelu(float x){ return x > 0.f ? x : 0.2f * x; }

// ---------------- CSR build ----------------
__global__ __launch_bounds__(256) void k_init(int* __restrict__ cnt){
  int i = blockIdx.x * 256 + threadIdx.x;
  if(i < NTOT) cnt[i] = 0;
}

__global__ __launch_bounds__(256) void k_count(const int* __restrict__ ei, int* __restrict__ cnt){
  int e = blockIdx.x * 256 + threadIdx.x;
  if(e < E_) atomicAdd(&cnt[ei[E_ + e]], 1);
}

__global__ __launch_bounds__(1024) void k_scan(const int* __restrict__ cnt,
                                               int* __restrict__ rowst,
                                               int* __restrict__ cursor){
  __shared__ int lds[1024];
  const int t = threadIdx.x;
  int loc[8];
  int s = 0;
  #pragma unroll
  for(int i = 0; i < 8; i++){ loc[i] = s; s += cnt[t * 8 + i]; }
  lds[t] = s;
  __syncthreads();
  for(int off = 1; off < 1024; off <<= 1){
    int v = lds[t];
    int a = (t >= off) ? lds[t - off] : 0;
    __syncthreads();
    lds[t] = v + a;
    __syncthreads();
  }
  const int base = (t > 0) ? lds[t - 1] : 0;
  #pragma unroll
  for(int i = 0; i < 8; i++){
    rowst[t * 8 + i] = base + loc[i];
    cursor[t * 8 + i] = 0;
  }
  if(t == 1023) rowst[NTOT] = lds[1023];
}

__global__ __launch_bounds__(256) void k_fill(const int* __restrict__ ei,
                                              const int* __restrict__ rowst,
                                              int* __restrict__ cursor,
                                              int* __restrict__ csr,
                                              int* __restrict__ csr_dst){
  int e = blockIdx.x * 256 + threadIdx.x;
  if(e < E_){
    int d = ei[E_ + e];
    int pos = atomicAdd(&cursor[d], 1);
    csr[rowst[d] + pos] = ei[e];
    csr_dst[rowst[d] + pos] = d;
  }
}

// ---- gate-permuted fp32->bf16 LSTM weights (4 matrices via blockIdx.y) ----
__global__ __launch_bounds__(256) void k_wperm(const float* __restrict__ s0, u16* __restrict__ d0,
                                               const float* __restrict__ s1, u16* __restrict__ d1,
                                               const float* __restrict__ s2, u16* __restrict__ d2,
                                               const float* __restrict__ s3, u16* __restrict__ d3){
  const float* src = blockIdx.y == 0 ? s0 : blockIdx.y == 1 ? s1 : blockIdx.y == 2 ? s2 : s3;
  u16* dst = blockIdx.y == 0 ? d0 : blockIdx.y == 1 ? d1 : blockIdx.y == 2 ? d2 : d3;
  int i = blockIdx.x * 256 + threadIdx.x;
  if(i < 512 * 128){
    int p = i >> 7, k = i & 127;
    int w = p >> 6, g = (p >> 4) & 3, l = p & 15;
    int row = g * 128 + w * 16 + l;
    dst[i] = f2bf(src[row * 128 + k]);
  }
}

// ---- GAT W (F x H fp32) -> W^T (H x F bf16) for MFMA B-fragments ----
__global__ __launch_bounds__(256) void k_wtc(const float* __restrict__ W, u16* __restrict__ Wt){
  int i = blockIdx.x * 256 + threadIdx.x;   // i over H*F
  if(i < H_ * F_){
    int nn = i >> 6, f = i & 63;
    Wt[i] = f2bf(W[f * H_ + nn]);
  }
}

// ---------------- MFMA GAT projection + attention coefficients ----------------
__global__ __launch_bounds__(256) void k_projm(const float* __restrict__ x,
    const u16* __restrict__ Wt, const float* __restrict__ att_s, const float* __restrict__ att_d,
    u16* __restrict__ hbuf, float* __restrict__ asrc, float* __restrict__ adst){
  const int tid  = threadIdx.x;
  const int wave = tid >> 6;
  const int lane = tid & 63;
  const int l15  = lane & 15;
  const int quad = lane >> 4;
  const int r0   = blockIdx.x * 64 + wave * 16;
  const int row  = r0 + l15;
  const int t = row >> 13, nt = row & 8191;
  const int b = nt >> 11, n = nt & 2047;
  const float* xrow = x + (((size_t)b * T_ + t) * N_ + n) * F_;

  bf16x8 a[2];
  #pragma unroll
  for(int ks = 0; ks < 2; ks++){
    const float4 f0 = *(const float4*)(xrow + ks * 32 + quad * 8);
    const float4 f1 = *(const float4*)(xrow + ks * 32 + quad * 8 + 4);
    bf16x8 av;
    av[0] = (__bf16)f0.x; av[1] = (__bf16)f0.y; av[2] = (__bf16)f0.z; av[3] = (__bf16)f0.w;
    av[4] = (__bf16)f1.x; av[5] = (__bf16)f1.y; av[6] = (__bf16)f1.z; av[7] = (__bf16)f1.w;
    a[ks] = av;
  }

  f32x4 acc[8];
  #pragma unroll
  for(int c = 0; c < 8; c++){ f32x4 z = {0.f,0.f,0.f,0.f}; acc[c] = z; }
  #pragma unroll
  for(int c = 0; c < 8; c++){
    #pragma unroll
    for(int ks = 0; ks < 2; ks++){
      const bf16x8 bv = *(const bf16x8*)(Wt + (c * 16 + l15) * F_ + ks * 32 + quad * 8);
      acc[c] = __builtin_amdgcn_mfma_f32_16x16x32_bf16(a[ks], bv, acc[c], 0, 0, 0);
    }
  }

  float ps[4][4], pd[4][4];   // [r][head]
  #pragma unroll
  for(int r = 0; r < 4; r++)
    #pragma unroll
    for(int h = 0; h < 4; h++){ ps[r][h] = 0.f; pd[r][h] = 0.f; }

  #pragma unroll
  for(int c = 0; c < 8; c++){
    const int col = c * 16 + l15;
    const float asv = att_s[col];
    const float adv = att_d[col];
    const int head = c >> 1;
    #pragma unroll
    for(int r = 0; r < 4; r++){
      const float v = acc[c][r];
      hbuf[(size_t)(r0 + quad * 4 + r) * H_ + col] = f2bf(v);
      ps[r][head] += v * asv;
      pd[r][head] += v * adv;
    }
  }
  #pragma unroll
  for(int m = 8; m >= 1; m >>= 1){
    #pragma unroll
    for(int r = 0; r < 4; r++)
      #pragma unroll
      for(int h = 0; h < 4; h++){
        ps[r][h] += __shfl_xor(ps[r][h], m);
        pd[r][h] += __shfl_xor(pd[r][h], m);
      }
  }
  if(l15 == 0){
    #pragma unroll
    for(int r = 0; r < 4; r++){
      const int rw = r0 + quad * 4 + r;
      #pragma unroll
      for(int h = 0; h < 4; h++){
        asrc[(size_t)rw * NHEADS + h] = ps[r][h];
        adst[(size_t)rw * NHEADS + h] = pd[r][h];
      }
    }
  }
}

// ---------------- GAT P1: per-(t,node,head) softmax max+denominator ----------------
__global__ __launch_bounds__(256) void k_mden(const float* __restrict__ asrc,
    const float* __restrict__ adst, const int* __restrict__ rowst, const int* __restrict__ csr,
    float* __restrict__ m_, float* __restrict__ den_){
  const int gid = blockIdx.x * 256 + threadIdx.x;   // (t,node,head), head fastest
  const int head = gid & 3;
  const int node = (gid >> 2) & 8191;
  const int t = gid >> 15;
  const int rbase = t * NTOT;
  const float ad = adst[(size_t)(rbase + node) * NHEADS + head];
  float m = lrelu(asrc[(size_t)(rbase + node) * NHEADS + head] + ad);  // self-loop
  float den = 1.f;
  const int rs = rowst[node], re = rowst[node + 1];
  for(int i = rs; i < re; i++){
    const int s = csr[i];
    const float ev = lrelu(asrc[(size_t)(rbase + s) * NHEADS + head] + ad);
    const float nm = fmaxf(m, ev);
    den = den * __expf(m - nm) + __expf(ev - nm);
    m = nm;
  }
  m_[gid] = m;
  den_[gid] = den;
}

// ---------------- GAT P2: per-(t,csrpos) alpha for all 4 heads ----------------
__global__ __launch_bounds__(256) void k_alpha(const float* __restrict__ asrc,
    const float* __restrict__ adst, const int* __restrict__ csr, const int* __restrict__ csr_dst,
    const float* __restrict__ m_, const float* __restrict__ den_, float* __restrict__ alphaC){
  const int p = blockIdx.x * 256 + threadIdx.x;   // 0..EF-1
  const int t = blockIdx.y;
  const int rbase = t * NTOT;
  int s, d;
  if(p < E_){ s = csr[p]; d = csr_dst[p]; } else { s = d = p - E_; }
  const float4 as4 = *(const float4*)&asrc[(size_t)(rbase + s) * NHEADS];
  const float4 ad4 = *(const float4*)&adst[(size_t)(rbase + d) * NHEADS];
  const float4 m4  = *(const float4*)&m_[(size_t)(rbase + d) * NHEADS];
  const float4 dn4 = *(const float4*)&den_[(size_t)(rbase + d) * NHEADS];
  float4 o;
  o.x = __expf(lrelu(as4.x + ad4.x) - m4.x) / dn4.x;
  o.y = __expf(lrelu(as4.y + ad4.y) - m4.y) / dn4.y;
  o.z = __expf(lrelu(as4.z + ad4.z) - m4.z) / dn4.z;
  o.w = __expf(lrelu(as4.w + ad4.w) - m4.w) / dn4.w;
  *(float4*)&alphaC[((size_t)t * EF + p) * NHEADS] = o;
}

// ---------------- GAT P3: aggregation; wave per (t,node), lane covers dims (lane, lane+64) ----------------
__global__ __launch_bounds__(256) void k_agg(const u16* __restrict__ hbuf,
    const float* __restrict__ alphaC, const int* __restrict__ rowst, const int* __restrict__ csr,
    const float* __restrict__ gbias, u16* __restrict__ spat){
  const int tid = threadIdx.x;
  const int wave = tid >> 6;
  const int lane = tid & 63;
  const int task = blockIdx.x * 4 + wave;
  const int node = task & 8191;
  const int t = task >> 13;
  const int rbase = t * NTOT;
  const int d0 = lane, d1 = lane + 64;

  const float4 aself = *(const float4*)&alphaC[((size_t)t * EF + E_ + node) * NHEADS];
  float acc0 = (lane < 32 ? aself.x : aself.y) * bf2f(hbuf[(size_t)(rbase + node) * H_ + d0]);
  float acc1 = (lane < 32 ? aself.z : aself.w) * bf2f(hbuf[(size_t)(rbase + node) * H_ + d1]);
  const int rs = rowst[node], re = rowst[node + 1];
  for(int i = rs; i < re; i++){
    const int s = csr[i];
    const float4 av = *(const float4*)&alphaC[((size_t)t * EF + i) * NHEADS];
    const float a0 = lane < 32 ? av.x : av.y;
    const float a1 = lane < 32 ? av.z : av.w;
    acc0 += a0 * bf2f(hbuf[(size_t)(rbase + s) * H_ + d0]);
    acc1 += a1 * bf2f(hbuf[(size_t)(rbase + s) * H_ + d1]);
  }
  const float v0 = acc0 + gbias[d0];
  const float v1 = acc1 + gbias[d1];
  spat[(size_t)(rbase + node) * H_ + d0] = f2bf(v0 > 0.f ? v0 : 0.f);
  spat[(size_t)(rbase + node) * H_ + d1] = f2bf(v1 > 0.f ? v1 : 0.f);
}

// ---------------- 2-layer LSTM: gate-permuted MFMA, in-register epilogue ----------------
// ks-loop NOT unrolled: keeps live fragments to one iteration (~105 regs) -> no scratch spill.
__global__ __launch_bounds__(512) __attribute__((amdgpu_waves_per_eu(2))) void k_lstm(
    const u16* __restrict__ spat,
    const u16* __restrict__ Wp_ih0, const u16* __restrict__ Wp_hh0,
    const float* __restrict__ bih0, const float* __restrict__ bhh0,
    const u16* __restrict__ Wp_ih1, const u16* __restrict__ Wp_hh1,
    const float* __restrict__ bih1, const float* __restrict__ bhh1,
    float* __restrict__ h1f)
{
  __shared__ __align__(16) u16 h0s[2][32 * HPAD];  // 2 x 8.5 KB
  __shared__ __align__(16) u16 h1s[2][32 * HPAD];

  const int tid  = threadIdx.x;
  const int wave = tid >> 6;
  const int lane = tid & 63;
  const int l15  = lane & 15;
  const int quad = lane >> 4;
  const int n0   = blockIdx.x * 32;
  const int dim  = wave * 16 + l15;

  for(int i = tid; i < 2 * 32 * HPAD; i += 512){
    ((u16*)h0s)[i] = 0; ((u16*)h1s)[i] = 0;
  }
  float cst[16];
  #pragma unroll
  for(int i = 0; i < 16; i++) cst[i] = 0.f;

  float bias[2][4];
  #pragma unroll
  for(int g = 0; g < 4; g++){
    bias[0][g] = bih0[g * 128 + dim] + bhh0[g * 128 + dim];
    bias[1][g] = bih1[g * 128 + dim] + bhh1[g * 128 + dim];
  }
  __syncthreads();

  #pragma unroll 1
  for(int t = 0; t < T_; t++){
    const u16* xrow = spat + (size_t)t * NTOT * H_;
    const int rp = t & 1, wp = rp ^ 1;
    #pragma unroll
    for(int layer = 0; layer < 2; layer++){
      const u16* Wih = layer ? Wp_ih1 : Wp_ih0;
      const u16* Whh = layer ? Wp_hh1 : Wp_hh0;
      const u16* hpv = layer ? h1s[rp] : h0s[rp];
      f32x4 acc[2][4];
      #pragma unroll
      for(int nt = 0; nt < 4; nt++){
        const float bv = bias[layer][nt];
        f32x4 b4 = {bv, bv, bv, bv};
        acc[0][nt] = b4; acc[1][nt] = b4;
      }
      #pragma unroll 1
      for(int ks = 0; ks < 4; ks++){
        const int k = ks * 32 + quad * 8;  // A[m=lane&15][k=quad*8+j]
        bf16x8 a1[2], a2[2];
        #pragma unroll
        for(int mt = 0; mt < 2; mt++){
          if(layer == 0)
            a1[mt] = *(const bf16x8*)(xrow + (size_t)(n0 + mt * 16 + l15) * H_ + k);
          else
            a1[mt] = *(const bf16x8*)(h0s[wp] + (mt * 16 + l15) * HPAD + k);
          a2[mt] = *(const bf16x8*)(hpv + (mt * 16 + l15) * HPAD + k);
        }
        #pragma unroll
        for(int nt = 0; nt < 4; nt++){
          const int row = wave * 64 + nt * 16 + l15;   // permuted weight row
          const bf16x8 b1 = *(const bf16x8*)(Wih + row * H_ + k);
          const bf16x8 b2 = *(const bf16x8*)(Whh + row * H_ + k);
          #pragma unroll
          for(int mt = 0; mt < 2; mt++){
            acc[mt][nt] = __builtin_amdgcn_mfma_f32_16x16x32_bf16(a1[mt], b1, acc[mt][nt], 0, 0, 0);
            acc[mt][nt] = __builtin_amdgcn_mfma_f32_16x16x32_bf16(a2[mt], b2, acc[mt][nt], 0, 0, 0);
          }
        }
      }
      // in-register epilogue: C/D row = quad*4 + r (node), this lane's dim fixed
      u16* hcur = layer ? h1s[wp] : h0s[wp];
      #pragma unroll
      for(int mt = 0; mt < 2; mt++){
        #pragma unroll
        for(int r = 0; r < 4; r++){
          const int node = mt * 16 + quad * 4 + r;
          const float gi = acc[mt][0][r];
          const float gf = acc[mt][1][r];
          const float gg = acc[mt][2][r];
          const float go = acc[mt][3][r];
          const int ci = layer * 8 + mt * 4 + r;
          const float c = sigf(gf) * cst[ci] + sigf(gi) * tanhfast(gg);
          cst[ci] = c;
          const float hv = sigf(go) * tanhfast(c);
          hcur[node * HPAD + dim] = f2bf(hv);
          if(layer == 1 && t == T_ - 1)
            h1f[(size_t)(n0 + node) * H_ + dim] = hv;
        }
      }
      __syncthreads();
    }
  }
}

// ---------------- LayerNorm: one wave per node, shuffle-only, fp32 output ----------------
__global__ __launch_bounds__(64) void k_ln(const float* __restrict__ h1f,
    const float* __restrict__ g, const float* __restrict__ b, float* __restrict__ out){
  const int node = blockIdx.x;
  const int tid = threadIdx.x;
  const float v0 = h1f[(size_t)node * H_ + tid];
  const float v1 = h1f[(size_t)node * H_ + 64 + tid];
  float s = v0 + v1;
  #pragma unroll
  for(int m = 32; m >= 1; m >>= 1) s += __shfl_xor(s, m);
  const float mu = s * (1.f / H_);
  const float d0 = v0 - mu, d1 = v1 - mu;
  s = d0 * d0 + d1 * d1;
  #pragma unroll
  for(int m = 32; m >= 1; m >>= 1) s += __shfl_xor(s, m);
  const float rstd = rsqrtf(s * (1.f / H_) + 1e-5f);
  out[(size_t)node * H_ + tid]      = d0 * rstd * g[tid]      + b[tid];
  out[(size_t)node * H_ + 64 + tid] = d1 * rstd * g[64 + tid] + b[64 + tid];
}

extern "C" void kernel_launch(void* const* d_in, const int* in_sizes, int n_in,
                              void* d_out, int out_size, void* d_ws, size_t ws_size,
                              hipStream_t stream) {
  (void)in_sizes; (void)n_in; (void)out_size; (void)ws_size;
  const float* x     = (const float*)d_in[0];
  const float* W     = (const float*)d_in[1];
  const float* att_s = (const float*)d_in[2];
  const float* att_d = (const float*)d_in[3];
  const float* gbias = (const float*)d_in[4];
  const float* Wih0  = (const float*)d_in[5];
  const float* Whh0  = (const float*)d_in[6];
  const float* bih0  = (const float*)d_in[7];
  const float* bhh0  = (const float*)d_in[8];
  const float* Wih1  = (const float*)d_in[9];
  const float* Whh1  = (const float*)d_in[10];
  const float* bih1  = (const float*)d_in[11];
  const float* bhh1  = (const float*)d_in[12];
  const float* lng   = (const float*)d_in[13];
  const float* lnb   = (const float*)d_in[14];
  const int*   ei    = (const int*)d_in[15];
  float* out = (float*)d_out;

  char* p = (char*)d_ws;
  auto carve = [&](size_t bytes) -> void* {
    void* r = (void*)p;
    p += (bytes + 255) & ~(size_t)255;
    return r;
  };
  u16* Wp_ih0 = (u16*)carve(512 * 128 * 2);
  u16* Wp_hh0 = (u16*)carve(512 * 128 * 2);
  u16* Wp_ih1 = (u16*)carve(512 * 128 * 2);
  u16* Wp_hh1 = (u16*)carve(512 * 128 * 2);
  u16* Wt     = (u16*)carve(H_ * F_ * 2);
  u16*   hbuf   = (u16*)carve((size_t)T_ * NTOT * H_ * 2);           // 21 MB bf16
  float* asrc   = (float*)carve((size_t)T_ * NTOT * NHEADS * 4);
  float* adst   = (float*)carve((size_t)T_ * NTOT * NHEADS * 4);
  float* m_     = (float*)carve((size_t)T_ * NTOT * NHEADS * 4);
  float* den_   = (float*)carve((size_t)T_ * NTOT * NHEADS * 4);
  float* alphaC = (float*)carve((size_t)T_ * EF * NHEADS * 4);       // 11.8 MB
  float* h1f    = (float*)carve((size_t)NTOT * H_ * 4);
  u16*   spat   = (u16*)carve((size_t)T_ * NTOT * H_ * 2);           // 21 MB bf16
  int*   cnt    = (int*)carve(NTOT * 4);
  int*   curs   = (int*)carve(NTOT * 4);
  int*   rowst  = (int*)carve((NTOT + 1) * 4);
  int*   csr    = (int*)carve((size_t)E_ * 4);
  int*   csrd   = (int*)carve((size_t)E_ * 4);

  hipLaunchKernelGGL(k_init,  dim3(32),        dim3(256),  0, stream, cnt);
  hipLaunchKernelGGL(k_count, dim3(256),       dim3(256),  0, stream, ei, cnt);
  hipLaunchKernelGGL(k_scan,  dim3(1),         dim3(1024), 0, stream, cnt, rowst, curs);
  hipLaunchKernelGGL(k_fill,  dim3(256),       dim3(256),  0, stream, ei, rowst, curs, csr, csrd);
  hipLaunchKernelGGL(k_wperm, dim3(256, 4),    dim3(256),  0, stream,
                     Wih0, Wp_ih0, Whh0, Wp_hh0, Wih1, Wp_ih1, Whh1, Wp_hh1);
  hipLaunchKernelGGL(k_wtc,   dim3(32),        dim3(256),  0, stream, W, Wt);
  hipLaunchKernelGGL(k_projm, dim3(1280),      dim3(256),  0, stream, x, Wt, att_s, att_d, hbuf, asrc, adst);
  hipLaunchKernelGGL(k_mden,  dim3(1280),      dim3(256),  0, stream, asrc, adst, rowst, csr, m_, den_);
  hipLaunchKernelGGL(k_alpha, dim3(288, 10),   dim3(256),  0, stream, asrc, adst, csr, csrd, m_, den_, alphaC);
  hipLaunchKernelGGL(k_agg,   dim3(20480),     dim3(256),  0, stream, hbuf, alphaC, rowst, csr, gbias, spat);
  hipLaunchKernelGGL(k_lstm,  dim3(256),       dim3(512),  0, stream, spat,
                     Wp_ih0, Wp_hh0, bih0, bhh0, Wp_ih1, Wp_hh1, bih1, bhh1, h1f);
  hipLaunchKernelGGL(k_ln,    dim3(8192),      dim3(64),   0, stream, h1f, lng, lnb, out);
}

// Round 12
// 401.855 us; speedup vs baseline: 3.2870x; 1.0748x over previous
//
#include <hip/hip_runtime.h>

#define T_ 10
#define B_ 4
#define N_ 2048
#define NTOT 8192
#define F_ 64
#define H_ 128
#define NHEADS 4
#define D_ 32
#define E_ 65536
#define EF 73728          // E + NTOT self-loops
#define HPAD 136

typedef __bf16 bf16x8 __attribute__((ext_vector_type(8)));
typedef float f32x4 __attribute__((ext_vector_type(4)));
typedef unsigned short u16;

__device__ __forceinline__ float bf2f(u16 u){
  union { unsigned int i; float f; } v; v.i = ((unsigned int)u) << 16; return v.f;
}
__device__ __forceinline__ u16 f2bf(float f){
  union { float f; unsigned int i; } v; v.f = f;
  return (u16)((v.i + 0x7FFFu + ((v.i >> 16) & 1u)) >> 16);
}
__device__ __forceinline__ float sigf(float x){ return 1.f / (1.f + __expf(-x)); }
__device__ __forceinline__ float tanhfast(float x){ return 1.f - 2.f / (__expf(2.f * x) + 1.f); }
__device__ __forceinline__ float lrelu(float x){ return x > 0.f ? x : 0.2f * x; }

// ---------------- CSR build ----------------
__global__ __launch_bounds__(256) void k_init(int* __restrict__ cnt){
  int i = blockIdx.x * 256 + threadIdx.x;
  if(i < NTOT) cnt[i] = 0;
}

__global__ __launch_bounds__(256) void k_count(const int* __restrict__ ei, int* __restrict__ cnt){
  int e = blockIdx.x * 256 + threadIdx.x;
  if(e < E_) atomicAdd(&cnt[ei[E_ + e]], 1);
}

__global__ __launch_bounds__(1024) void k_scan(const int* __restrict__ cnt,
                                               int* __restrict__ rowst,
                                               int* __restrict__ cursor){
  __shared__ int lds[1024];
  const int t = threadIdx.x;
  int loc[8];
  int s = 0;
  #pragma unroll
  for(int i = 0; i < 8; i++){ loc[i] = s; s += cnt[t * 8 + i]; }
  lds[t] = s;
  __syncthreads();
  for(int off = 1; off < 1024; off <<= 1){
    int v = lds[t];
    int a = (t >= off) ? lds[t - off] : 0;
    __syncthreads();
    lds[t] = v + a;
    __syncthreads();
  }
  const int base = (t > 0) ? lds[t - 1] : 0;
  #pragma unroll
  for(int i = 0; i < 8; i++){
    rowst[t * 8 + i] = base + loc[i];
    cursor[t * 8 + i] = 0;
  }
  if(t == 1023) rowst[NTOT] = lds[1023];
}

__global__ __launch_bounds__(256) void k_fill(const int* __restrict__ ei,
                                              const int* __restrict__ rowst,
                                              int* __restrict__ cursor,
                                              int* __restrict__ csr,
                                              int* __restrict__ csr_dst){
  int e = blockIdx.x * 256 + threadIdx.x;
  if(e < E_){
    int d = ei[E_ + e];
    int pos = atomicAdd(&cursor[d], 1);
    csr[rowst[d] + pos] = ei[e];
    csr_dst[rowst[d] + pos] = d;
  }
}

// ---- gate-permuted fp32->bf16 LSTM weights (4 matrices via blockIdx.y) ----
__global__ __launch_bounds__(256) void k_wperm(const float* __restrict__ s0, u16* __restrict__ d0,
                                               const float* __restrict__ s1, u16* __restrict__ d1,
                                               const float* __restrict__ s2, u16* __restrict__ d2,
                                               const float* __restrict__ s3, u16* __restrict__ d3){
  const float* src = blockIdx.y == 0 ? s0 : blockIdx.y == 1 ? s1 : blockIdx.y == 2 ? s2 : s3;
  u16* dst = blockIdx.y == 0 ? d0 : blockIdx.y == 1 ? d1 : blockIdx.y == 2 ? d2 : d3;
  int i = blockIdx.x * 256 + threadIdx.x;
  if(i < 512 * 128){
    int p = i >> 7, k = i & 127;
    int w = p >> 6, g = (p >> 4) & 3, l = p & 15;
    int row = g * 128 + w * 16 + l;
    dst[i] = f2bf(src[row * 128 + k]);
  }
}

// ---- GAT W (F x H fp32) -> W^T (H x F bf16) for MFMA B-fragments ----
__global__ __launch_bounds__(256) void k_wtc(const float* __restrict__ W, u16* __restrict__ Wt){
  int i = blockIdx.x * 256 + threadIdx.x;   // i over H*F
  if(i < H_ * F_){
    int nn = i >> 6, f = i & 63;
    Wt[i] = f2bf(W[f * H_ + nn]);
  }
}

// ---------------- MFMA GAT projection + attention coefficients ----------------
__global__ __launch_bounds__(256) void k_projm(const float* __restrict__ x,
    const u16* __restrict__ Wt, const float* __restrict__ att_s, const float* __restrict__ att_d,
    u16* __restrict__ hbuf, float* __restrict__ asrc, float* __restrict__ adst){
  const int tid  = threadIdx.x;
  const int wave = tid >> 6;
  const int lane = tid & 63;
  const int l15  = lane & 15;
  const int quad = lane >> 4;
  const int r0   = blockIdx.x * 64 + wave * 16;
  const int row  = r0 + l15;
  const int t = row >> 13, nt = row & 8191;
  const int b = nt >> 11, n = nt & 2047;
  const float* xrow = x + (((size_t)b * T_ + t) * N_ + n) * F_;

  bf16x8 a[2];
  #pragma unroll
  for(int ks = 0; ks < 2; ks++){
    const float4 f0 = *(const float4*)(xrow + ks * 32 + quad * 8);
    const float4 f1 = *(const float4*)(xrow + ks * 32 + quad * 8 + 4);
    bf16x8 av;
    av[0] = (__bf16)f0.x; av[1] = (__bf16)f0.y; av[2] = (__bf16)f0.z; av[3] = (__bf16)f0.w;
    av[4] = (__bf16)f1.x; av[5] = (__bf16)f1.y; av[6] = (__bf16)f1.z; av[7] = (__bf16)f1.w;
    a[ks] = av;
  }

  f32x4 acc[8];
  #pragma unroll
  for(int c = 0; c < 8; c++){ f32x4 z = {0.f,0.f,0.f,0.f}; acc[c] = z; }
  #pragma unroll
  for(int c = 0; c < 8; c++){
    #pragma unroll
    for(int ks = 0; ks < 2; ks++){
      const bf16x8 bv = *(const bf16x8*)(Wt + (c * 16 + l15) * F_ + ks * 32 + quad * 8);
      acc[c] = __builtin_amdgcn_mfma_f32_16x16x32_bf16(a[ks], bv, acc[c], 0, 0, 0);
    }
  }

  float ps[4][4], pd[4][4];   // [r][head]
  #pragma unroll
  for(int r = 0; r < 4; r++)
    #pragma unroll
    for(int h = 0; h < 4; h++){ ps[r][h] = 0.f; pd[r][h] = 0.f; }

  #pragma unroll
  for(int c = 0; c < 8; c++){
    const int col = c * 16 + l15;
    const float asv = att_s[col];
    const float adv = att_d[col];
    const int head = c >> 1;
    #pragma unroll
    for(int r = 0; r < 4; r++){
      const float v = acc[c][r];
      hbuf[(size_t)(r0 + quad * 4 + r) * H_ + col] = f2bf(v);
      ps[r][head] += v * asv;
      pd[r][head] += v * adv;
    }
  }
  #pragma unroll
  for(int m = 8; m >= 1; m >>= 1){
    #pragma unroll
    for(int r = 0; r < 4; r++)
      #pragma unroll
      for(int h = 0; h < 4; h++){
        ps[r][h] += __shfl_xor(ps[r][h], m);
        pd[r][h] += __shfl_xor(pd[r][h], m);
      }
  }
  if(l15 == 0){
    #pragma unroll
    for(int r = 0; r < 4; r++){
      const int rw = r0 + quad * 4 + r;
      #pragma unroll
      for(int h = 0; h < 4; h++){
        asrc[(size_t)rw * NHEADS + h] = ps[r][h];
        adst[(size_t)rw * NHEADS + h] = pd[r][h];
      }
    }
  }
}

// ---------------- GAT P1: per-(t,node,head) softmax max+denominator ----------------
__global__ __launch_bounds__(256) void k_mden(const float* __restrict__ asrc,
    const float* __restrict__ adst, const int* __restrict__ rowst, const int* __restrict__ csr,
    float* __restrict__ m_, float* __restrict__ den_){
  const int gid = blockIdx.x * 256 + threadIdx.x;   // (t,node,head), head fastest
  const int head = gid & 3;
  const int node = (gid >> 2) & 8191;
  const int t = gid >> 15;
  const int rbase = t * NTOT;
  const float ad = adst[(size_t)(rbase + node) * NHEADS + head];
  float m = lrelu(asrc[(size_t)(rbase + node) * NHEADS + head] + ad);  // self-loop
  float den = 1.f;
  const int rs = rowst[node], re = rowst[node + 1];
  for(int i = rs; i < re; i++){
    const int s = csr[i];
    const float ev = lrelu(asrc[(size_t)(rbase + s) * NHEADS + head] + ad);
    const float nm = fmaxf(m, ev);
    den = den * __expf(m - nm) + __expf(ev - nm);
    m = nm;
  }
  m_[gid] = m;
  den_[gid] = den;
}

// ---------------- GAT P2: per-(t,csrpos) alpha for all 4 heads ----------------
__global__ __launch_bounds__(256) void k_alpha(const float* __restrict__ asrc,
    const float* __restrict__ adst, const int* __restrict__ csr, const int* __restrict__ csr_dst,
    const float* __restrict__ m_, const float* __restrict__ den_, float* __restrict__ alphaC){
  const int p = blockIdx.x * 256 + threadIdx.x;   // 0..EF-1
  const int t = blockIdx.y;
  const int rbase = t * NTOT;
  int s, d;
  if(p < E_){ s = csr[p]; d = csr_dst[p]; } else { s = d = p - E_; }
  const float4 as4 = *(const float4*)&asrc[(size_t)(rbase + s) * NHEADS];
  const float4 ad4 = *(const float4*)&adst[(size_t)(rbase + d) * NHEADS];
  const float4 m4  = *(const float4*)&m_[(size_t)(rbase + d) * NHEADS];
  const float4 dn4 = *(const float4*)&den_[(size_t)(rbase + d) * NHEADS];
  float4 o;
  o.x = __expf(lrelu(as4.x + ad4.x) - m4.x) / dn4.x;
  o.y = __expf(lrelu(as4.y + ad4.y) - m4.y) / dn4.y;
  o.z = __expf(lrelu(as4.z + ad4.z) - m4.z) / dn4.z;
  o.w = __expf(lrelu(as4.w + ad4.w) - m4.w) / dn4.w;
  *(float4*)&alphaC[((size_t)t * EF + p) * NHEADS] = o;
}

// ---------------- GAT P3: aggregation; wave per (t,node), lane covers dims (lane, lane+64) ----------------
__global__ __launch_bounds__(256) void k_agg(const u16* __restrict__ hbuf,
    const float* __restrict__ alphaC, const int* __restrict__ rowst, const int* __restrict__ csr,
    const float* __restrict__ gbias, u16* __restrict__ spat){
  const int tid = threadIdx.x;
  const int wave = tid >> 6;
  const int lane = tid & 63;
  const int task = blockIdx.x * 4 + wave;
  const int node = task & 8191;
  const int t = task >> 13;
  const int rbase = t * NTOT;
  const int d0 = lane, d1 = lane + 64;

  const float4 aself = *(const float4*)&alphaC[((size_t)t * EF + E_ + node) * NHEADS];
  float acc0 = (lane < 32 ? aself.x : aself.y) * bf2f(hbuf[(size_t)(rbase + node) * H_ + d0]);
  float acc1 = (lane < 32 ? aself.z : aself.w) * bf2f(hbuf[(size_t)(rbase + node) * H_ + d1]);
  const int rs = rowst[node], re = rowst[node + 1];
  for(int i = rs; i < re; i++){
    const int s = csr[i];
    const float4 av = *(const float4*)&alphaC[((size_t)t * EF + i) * NHEADS];
    const float a0 = lane < 32 ? av.x : av.y;
    const float a1 = lane < 32 ? av.z : av.w;
    acc0 += a0 * bf2f(hbuf[(size_t)(rbase + s) * H_ + d0]);
    acc1 += a1 * bf2f(hbuf[(size_t)(rbase + s) * H_ + d1]);
  }
  const float v0 = acc0 + gbias[d0];
  const float v1 = acc1 + gbias[d1];
  spat[(size_t)(rbase + node) * H_ + d0] = f2bf(v0 > 0.f ? v0 : 0.f);
  spat[(size_t)(rbase + node) * H_ + d1] = f2bf(v1 > 0.f ? v1 : 0.f);
}

// ---------------- 2-layer LSTM: gate-permuted MFMA, in-register epilogue ----------------
// Full ks unroll (R9-style load batching) + waves_per_eu(2) (256-VGPR budget, honored per R11)
// -> compiler can hoist the whole layer-step's loads without spilling.
__global__ __launch_bounds__(512) __attribute__((amdgpu_waves_per_eu(2))) void k_lstm(
    const u16* __restrict__ spat,
    const u16* __restrict__ Wp_ih0, const u16* __restrict__ Wp_hh0,
    const float* __restrict__ bih0, const float* __restrict__ bhh0,
    const u16* __restrict__ Wp_ih1, const u16* __restrict__ Wp_hh1,
    const float* __restrict__ bih1, const float* __restrict__ bhh1,
    float* __restrict__ h1f)
{
  __shared__ __align__(16) u16 h0s[2][32 * HPAD];  // 2 x 8.5 KB
  __shared__ __align__(16) u16 h1s[2][32 * HPAD];

  const int tid  = threadIdx.x;
  const int wave = tid >> 6;
  const int lane = tid & 63;
  const int l15  = lane & 15;
  const int quad = lane >> 4;
  const int n0   = blockIdx.x * 32;
  const int dim  = wave * 16 + l15;

  for(int i = tid; i < 2 * 32 * HPAD; i += 512){
    ((u16*)h0s)[i] = 0; ((u16*)h1s)[i] = 0;
  }
  float cst[16];
  #pragma unroll
  for(int i = 0; i < 16; i++) cst[i] = 0.f;

  float bias[2][4];
  #pragma unroll
  for(int g = 0; g < 4; g++){
    bias[0][g] = bih0[g * 128 + dim] + bhh0[g * 128 + dim];
    bias[1][g] = bih1[g * 128 + dim] + bhh1[g * 128 + dim];
  }
  __syncthreads();

  #pragma unroll 1
  for(int t = 0; t < T_; t++){
    const u16* xrow = spat + (size_t)t * NTOT * H_;
    const int rp = t & 1, wp = rp ^ 1;
    #pragma unroll
    for(int layer = 0; layer < 2; layer++){
      const u16* Wih = layer ? Wp_ih1 : Wp_ih0;
      const u16* Whh = layer ? Wp_hh1 : Wp_hh0;
      const u16* hpv = layer ? h1s[rp] : h0s[rp];
      f32x4 acc[2][4];
      #pragma unroll
      for(int nt = 0; nt < 4; nt++){
        const float bv = bias[layer][nt];
        f32x4 b4 = {bv, bv, bv, bv};
        acc[0][nt] = b4; acc[1][nt] = b4;
      }
      #pragma unroll
      for(int ks = 0; ks < 4; ks++){
        const int k = ks * 32 + quad * 8;  // A[m=lane&15][k=quad*8+j]
        bf16x8 a1[2], a2[2];
        #pragma unroll
        for(int mt = 0; mt < 2; mt++){
          if(layer == 0)
            a1[mt] = *(const bf16x8*)(xrow + (size_t)(n0 + mt * 16 + l15) * H_ + k);
          else
            a1[mt] = *(const bf16x8*)(h0s[wp] + (mt * 16 + l15) * HPAD + k);
          a2[mt] = *(const bf16x8*)(hpv + (mt * 16 + l15) * HPAD + k);
        }
        #pragma unroll
        for(int nt = 0; nt < 4; nt++){
          const int row = wave * 64 + nt * 16 + l15;   // permuted weight row
          const bf16x8 b1 = *(const bf16x8*)(Wih + row * H_ + k);
          const bf16x8 b2 = *(const bf16x8*)(Whh + row * H_ + k);
          #pragma unroll
          for(int mt = 0; mt < 2; mt++){
            acc[mt][nt] = __builtin_amdgcn_mfma_f32_16x16x32_bf16(a1[mt], b1, acc[mt][nt], 0, 0, 0);
            acc[mt][nt] = __builtin_amdgcn_mfma_f32_16x16x32_bf16(a2[mt], b2, acc[mt][nt], 0, 0, 0);
          }
        }
      }
      // in-register epilogue: C/D row = quad*4 + r (node), this lane's dim fixed
      u16* hcur = layer ? h1s[wp] : h0s[wp];
      #pragma unroll
      for(int mt = 0; mt < 2; mt++){
        #pragma unroll
        for(int r = 0; r < 4; r++){
          const int node = mt * 16 + quad * 4 + r;
          const float gi = acc[mt][0][r];
          const float gf = acc[mt][1][r];
          const float gg = acc[mt][2][r];
          const float go = acc[mt][3][r];
          const int ci = layer * 8 + mt * 4 + r;
          const float c = sigf(gf) * cst[ci] + sigf(gi) * tanhfast(gg);
          cst[ci] = c;
          const float hv = sigf(go) * tanhfast(c);
          hcur[node * HPAD + dim] = f2bf(hv);
          if(layer == 1 && t == T_ - 1)
            h1f[(size_t)(n0 + node) * H_ + dim] = hv;
        }
      }
      __syncthreads();
    }
  }
}

// ---------------- LayerNorm: one wave per node, shuffle-only, fp32 output ----------------
__global__ __launch_bounds__(64) void k_ln(const float* __restrict__ h1f,
    const float* __restrict__ g, const float* __restrict__ b, float* __restrict__ out){
  const int node = blockIdx.x;
  const int tid = threadIdx.x;
  const float v0 = h1f[(size_t)node * H_ + tid];
  const float v1 = h1f[(size_t)node * H_ + 64 + tid];
  float s = v0 + v1;
  #pragma unroll
  for(int m = 32; m >= 1; m >>= 1) s += __shfl_xor(s, m);
  const float mu = s * (1.f / H_);
  const float d0 = v0 - mu, d1 = v1 - mu;
  s = d0 * d0 + d1 * d1;
  #pragma unroll
  for(int m = 32; m >= 1; m >>= 1) s += __shfl_xor(s, m);
  const float rstd = rsqrtf(s * (1.f / H_) + 1e-5f);
  out[(size_t)node * H_ + tid]      = d0 * rstd * g[tid]      + b[tid];
  out[(size_t)node * H_ + 64 + tid] = d1 * rstd * g[64 + tid] + b[64 + tid];
}

extern "C" void kernel_launch(void* const* d_in, const int* in_sizes, int n_in,
                              void* d_out, int out_size, void* d_ws, size_t ws_size,
                              hipStream_t stream) {
  (void)in_sizes; (void)n_in; (void)out_size; (void)ws_size;
  const float* x     = (const float*)d_in[0];
  const float* W     = (const float*)d_in[1];
  const float* att_s = (const float*)d_in[2];
  const float* att_d = (const float*)d_in[3];
  const float* gbias = (const float*)d_in[4];
  const float* Wih0  = (const float*)d_in[5];
  const float* Whh0  = (const float*)d_in[6];
  const float* bih0  = (const float*)d_in[7];
  const float* bhh0  = (const float*)d_in[8];
  const float* Wih1  = (const float*)d_in[9];
  const float* Whh1  = (const float*)d_in[10];
  const float* bih1  = (const float*)d_in[11];
  const float* bhh1  = (const float*)d_in[12];
  const float* lng   = (const float*)d_in[13];
  const float* lnb   = (const float*)d_in[14];
  const int*   ei    = (const int*)d_in[15];
  float* out = (float*)d_out;

  char* p = (char*)d_ws;
  auto carve = [&](size_t bytes) -> void* {
    void* r = (void*)p;
    p += (bytes + 255) & ~(size_t)255;
    return r;
  };
  u16* Wp_ih0 = (u16*)carve(512 * 128 * 2);
  u16* Wp_hh0 = (u16*)carve(512 * 128 * 2);
  u16* Wp_ih1 = (u16*)carve(512 * 128 * 2);
  u16* Wp_hh1 = (u16*)carve(512 * 128 * 2);
  u16* Wt     = (u16*)carve(H_ * F_ * 2);
  u16*   hbuf   = (u16*)carve((size_t)T_ * NTOT * H_ * 2);           // 21 MB bf16
  float* asrc   = (float*)carve((size_t)T_ * NTOT * NHEADS * 4);
  float* adst   = (float*)carve((size_t)T_ * NTOT * NHEADS * 4);
  float* m_     = (float*)carve((size_t)T_ * NTOT * NHEADS * 4);
  float* den_   = (float*)carve((size_t)T_ * NTOT * NHEADS * 4);
  float* alphaC = (float*)carve((size_t)T_ * EF * NHEADS * 4);       // 11.8 MB
  float* h1f    = (float*)carve((size_t)NTOT * H_ * 4);
  u16*   spat   = (u16*)carve((size_t)T_ * NTOT * H_ * 2);           // 21 MB bf16
  int*   cnt    = (int*)carve(NTOT * 4);
  int*   curs   = (int*)carve(NTOT * 4);
  int*   rowst  = (int*)carve((NTOT + 1) * 4);
  int*   csr    = (int*)carve((size_t)E_ * 4);
  int*   csrd   = (int*)carve((size_t)E_ * 4);

  hipLaunchKernelGGL(k_init,  dim3(32),        dim3(256),  0, stream, cnt);
  hipLaunchKernelGGL(k_count, dim3(256),       dim3(256),  0, stream, ei, cnt);
  hipLaunchKernelGGL(k_scan,  dim3(1),         dim3(1024), 0, stream, cnt, rowst, curs);
  hipLaunchKernelGGL(k_fill,  dim3(256),       dim3(256),  0, stream, ei, rowst, curs, csr, csrd);
  hipLaunchKernelGGL(k_wperm, dim3(256, 4),    dim3(256),  0, stream,
                     Wih0, Wp_ih0, Whh0, Wp_hh0, Wih1, Wp_ih1, Whh1, Wp_hh1);
  hipLaunchKernelGGL(k_wtc,   dim3(32),        dim3(256),  0, stream, W, Wt);
  hipLaunchKernelGGL(k_projm, dim3(1280),      dim3(256),  0, stream, x, Wt, att_s, att_d, hbuf, asrc, adst);
  hipLaunchKernelGGL(k_mden,  dim3(1280),      dim3(256),  0, stream, asrc, adst, rowst, csr, m_, den_);
  hipLaunchKernelGGL(k_alpha, dim3(288, 10),   dim3(256),  0, stream, asrc, adst, csr, csrd, m_, den_, alphaC);
  hipLaunchKernelGGL(k_agg,   dim3(20480),     dim3(256),  0, stream, hbuf, alphaC, rowst, csr, gbias, spat);
  hipLaunchKernelGGL(k_lstm,  dim3(256),       dim3(512),  0, stream, spat,
                     Wp_ih0, Wp_hh0, bih0, bhh0, Wp_ih1, Wp_hh1, bih1, bhh1, h1f);
  hipLaunchKernelGGL(k_ln,    dim3(8192),      dim3(64),   0, stream, h1f, lng, lnb, out);
}

// Round 13
// 392.507 us; speedup vs baseline: 3.3653x; 1.0238x over previous
//
#include <hip/hip_runtime.h>

#define T_ 10
#define B_ 4
#define N_ 2048
#define NTOT 8192
#define F_ 64
#define H_ 128
#define NHEADS 4
#define D_ 32
#define E_ 65536
#define EF 73728          // E + NTOT self-loops
#define HPAD 136
#define WROW 80           // staged weight row: 64B data + 16B pad (2-way LDS aliasing = free)

typedef __bf16 bf16x8 __attribute__((ext_vector_type(8)));
typedef float f32x4 __attribute__((ext_vector_type(4)));
typedef unsigned short u16;

__device__ __forceinline__ float bf2f(u16 u){
  union { unsigned int i; float f; } v; v.i = ((unsigned int)u) << 16; return v.f;
}
__device__ __forceinline__ u16 f2bf(float f){
  union { float f; unsigned int i; } v; v.f = f;
  return (u16)((v.i + 0x7FFFu + ((v.i >> 16) & 1u)) >> 16);
}
__device__ __forceinline__ float sigf(float x){ return 1.f / (1.f + __expf(-x)); }
__device__ __forceinline__ float tanhfast(float x){ return 1.f - 2.f / (__expf(2.f * x) + 1.f); }
__device__ __forceinline__ float lrelu(float x){ return x > 0.f ? x : 0.2f * x; }

// ---------------- CSR build ----------------
__global__ __launch_bounds__(256) void k_init(int* __restrict__ cnt){
  int i = blockIdx.x * 256 + threadIdx.x;
  if(i < NTOT) cnt[i] = 0;
}

__global__ __launch_bounds__(256) void k_count(const int* __restrict__ ei, int* __restrict__ cnt){
  int e = blockIdx.x * 256 + threadIdx.x;
  if(e < E_) atomicAdd(&cnt[ei[E_ + e]], 1);
}

__global__ __launch_bounds__(1024) void k_scan(const int* __restrict__ cnt,
                                               int* __restrict__ rowst,
                                               int* __restrict__ cursor){
  __shared__ int lds[1024];
  const int t = threadIdx.x;
  int loc[8];
  int s = 0;
  #pragma unroll
  for(int i = 0; i < 8; i++){ loc[i] = s; s += cnt[t * 8 + i]; }
  lds[t] = s;
  __syncthreads();
  for(int off = 1; off < 1024; off <<= 1){
    int v = lds[t];
    int a = (t >= off) ? lds[t - off] : 0;
    __syncthreads();
    lds[t] = v + a;
    __syncthreads();
  }
  const int base = (t > 0) ? lds[t - 1] : 0;
  #pragma unroll
  for(int i = 0; i < 8; i++){
    rowst[t * 8 + i] = base + loc[i];
    cursor[t * 8 + i] = 0;
  }
  if(t == 1023) rowst[NTOT] = lds[1023];
}

__global__ __launch_bounds__(256) void k_fill(const int* __restrict__ ei,
                                              const int* __restrict__ rowst,
                                              int* __restrict__ cursor,
                                              int* __restrict__ csr,
                                              int* __restrict__ csr_dst){
  int e = blockIdx.x * 256 + threadIdx.x;
  if(e < E_){
    int d = ei[E_ + e];
    int pos = atomicAdd(&cursor[d], 1);
    csr[rowst[d] + pos] = ei[e];
    csr_dst[rowst[d] + pos] = d;
  }
}

// ---- gate-permuted fp32->bf16 LSTM weights (4 matrices via blockIdx.y) ----
__global__ __launch_bounds__(256) void k_wperm(const float* __restrict__ s0, u16* __restrict__ d0,
                                               const float* __restrict__ s1, u16* __restrict__ d1,
                                               const float* __restrict__ s2, u16* __restrict__ d2,
                                               const float* __restrict__ s3, u16* __restrict__ d3){
  const float* src = blockIdx.y == 0 ? s0 : blockIdx.y == 1 ? s1 : blockIdx.y == 2 ? s2 : s3;
  u16* dst = blockIdx.y == 0 ? d0 : blockIdx.y == 1 ? d1 : blockIdx.y == 2 ? d2 : d3;
  int i = blockIdx.x * 256 + threadIdx.x;
  if(i < 512 * 128){
    int p = i >> 7, k = i & 127;
    int w = p >> 6, g = (p >> 4) & 3, l = p & 15;
    int row = g * 128 + w * 16 + l;
    dst[i] = f2bf(src[row * 128 + k]);
  }
}

// ---- GAT W (F x H fp32) -> W^T (H x F bf16) for MFMA B-fragments ----
__global__ __launch_bounds__(256) void k_wtc(const float* __restrict__ W, u16* __restrict__ Wt){
  int i = blockIdx.x * 256 + threadIdx.x;   // i over H*F
  if(i < H_ * F_){
    int nn = i >> 6, f = i & 63;
    Wt[i] = f2bf(W[f * H_ + nn]);
  }
}

// ---------------- MFMA GAT projection + attention coefficients ----------------
__global__ __launch_bounds__(256) void k_projm(const float* __restrict__ x,
    const u16* __restrict__ Wt, const float* __restrict__ att_s, const float* __restrict__ att_d,
    u16* __restrict__ hbuf, float* __restrict__ asrc, float* __restrict__ adst){
  const int tid  = threadIdx.x;
  const int wave = tid >> 6;
  const int lane = tid & 63;
  const int l15  = lane & 15;
  const int quad = lane >> 4;
  const int r0   = blockIdx.x * 64 + wave * 16;
  const int row  = r0 + l15;
  const int t = row >> 13, nt = row & 8191;
  const int b = nt >> 11, n = nt & 2047;
  const float* xrow = x + (((size_t)b * T_ + t) * N_ + n) * F_;

  bf16x8 a[2];
  #pragma unroll
  for(int ks = 0; ks < 2; ks++){
    const float4 f0 = *(const float4*)(xrow + ks * 32 + quad * 8);
    const float4 f1 = *(const float4*)(xrow + ks * 32 + quad * 8 + 4);
    bf16x8 av;
    av[0] = (__bf16)f0.x; av[1] = (__bf16)f0.y; av[2] = (__bf16)f0.z; av[3] = (__bf16)f0.w;
    av[4] = (__bf16)f1.x; av[5] = (__bf16)f1.y; av[6] = (__bf16)f1.z; av[7] = (__bf16)f1.w;
    a[ks] = av;
  }

  f32x4 acc[8];
  #pragma unroll
  for(int c = 0; c < 8; c++){ f32x4 z = {0.f,0.f,0.f,0.f}; acc[c] = z; }
  #pragma unroll
  for(int c = 0; c < 8; c++){
    #pragma unroll
    for(int ks = 0; ks < 2; ks++){
      const bf16x8 bv = *(const bf16x8*)(Wt + (c * 16 + l15) * F_ + ks * 32 + quad * 8);
      acc[c] = __builtin_amdgcn_mfma_f32_16x16x32_bf16(a[ks], bv, acc[c], 0, 0, 0);
    }
  }

  float ps[4][4], pd[4][4];   // [r][head]
  #pragma unroll
  for(int r = 0; r < 4; r++)
    #pragma unroll
    for(int h = 0; h < 4; h++){ ps[r][h] = 0.f; pd[r][h] = 0.f; }

  #pragma unroll
  for(int c = 0; c < 8; c++){
    const int col = c * 16 + l15;
    const float asv = att_s[col];
    const float adv = att_d[col];
    const int head = c >> 1;
    #pragma unroll
    for(int r = 0; r < 4; r++){
      const float v = acc[c][r];
      hbuf[(size_t)(r0 + quad * 4 + r) * H_ + col] = f2bf(v);
      ps[r][head] += v * asv;
      pd[r][head] += v * adv;
    }
  }
  #pragma unroll
  for(int m = 8; m >= 1; m >>= 1){
    #pragma unroll
    for(int r = 0; r < 4; r++)
      #pragma unroll
      for(int h = 0; h < 4; h++){
        ps[r][h] += __shfl_xor(ps[r][h], m);
        pd[r][h] += __shfl_xor(pd[r][h], m);
      }
  }
  if(l15 == 0){
    #pragma unroll
    for(int r = 0; r < 4; r++){
      const int rw = r0 + quad * 4 + r;
      #pragma unroll
      for(int h = 0; h < 4; h++){
        asrc[(size_t)rw * NHEADS + h] = ps[r][h];
        adst[(size_t)rw * NHEADS + h] = pd[r][h];
      }
    }
  }
}

// ---------------- GAT P1: per-(t,node,head) softmax max+denominator ----------------
__global__ __launch_bounds__(256) void k_mden(const float* __restrict__ asrc,
    const float* __restrict__ adst, const int* __restrict__ rowst, const int* __restrict__ csr,
    float* __restrict__ m_, float* __restrict__ den_){
  const int gid = blockIdx.x * 256 + threadIdx.x;   // (t,node,head), head fastest
  const int head = gid & 3;
  const int node = (gid >> 2) & 8191;
  const int t = gid >> 15;
  const int rbase = t * NTOT;
  const float ad = adst[(size_t)(rbase + node) * NHEADS + head];
  float m = lrelu(asrc[(size_t)(rbase + node) * NHEADS + head] + ad);  // self-loop
  float den = 1.f;
  const int rs = rowst[node], re = rowst[node + 1];
  for(int i = rs; i < re; i++){
    const int s = csr[i];
    const float ev = lrelu(asrc[(size_t)(rbase + s) * NHEADS + head] + ad);
    const float nm = fmaxf(m, ev);
    den = den * __expf(m - nm) + __expf(ev - nm);
    m = nm;
  }
  m_[gid] = m;
  den_[gid] = den;
}

// ---------------- GAT P2: per-(t,csrpos) alpha for all 4 heads ----------------
__global__ __launch_bounds__(256) void k_alpha(const float* __restrict__ asrc,
    const float* __restrict__ adst, const int* __restrict__ csr, const int* __restrict__ csr_dst,
    const float* __restrict__ m_, const float* __restrict__ den_, float* __restrict__ alphaC){
  const int p = blockIdx.x * 256 + threadIdx.x;   // 0..EF-1
  const int t = blockIdx.y;
  const int rbase = t * NTOT;
  int s, d;
  if(p < E_){ s = csr[p]; d = csr_dst[p]; } else { s = d = p - E_; }
  const float4 as4 = *(const float4*)&asrc[(size_t)(rbase + s) * NHEADS];
  const float4 ad4 = *(const float4*)&adst[(size_t)(rbase + d) * NHEADS];
  const float4 m4  = *(const float4*)&m_[(size_t)(rbase + d) * NHEADS];
  const float4 dn4 = *(const float4*)&den_[(size_t)(rbase + d) * NHEADS];
  float4 o;
  o.x = __expf(lrelu(as4.x + ad4.x) - m4.x) / dn4.x;
  o.y = __expf(lrelu(as4.y + ad4.y) - m4.y) / dn4.y;
  o.z = __expf(lrelu(as4.z + ad4.z) - m4.z) / dn4.z;
  o.w = __expf(lrelu(as4.w + ad4.w) - m4.w) / dn4.w;
  *(float4*)&alphaC[((size_t)t * EF + p) * NHEADS] = o;
}

// ---------------- GAT P3: aggregation; wave per (t,node), lane covers dims (lane, lane+64) ----------------
__global__ __launch_bounds__(256) void k_agg(const u16* __restrict__ hbuf,
    const float* __restrict__ alphaC, const int* __restrict__ rowst, const int* __restrict__ csr,
    const float* __restrict__ gbias, u16* __restrict__ spat){
  const int tid = threadIdx.x;
  const int wave = tid >> 6;
  const int lane = tid & 63;
  const int task = blockIdx.x * 4 + wave;
  const int node = task & 8191;
  const int t = task >> 13;
  const int rbase = t * NTOT;
  const int d0 = lane, d1 = lane + 64;

  const float4 aself = *(const float4*)&alphaC[((size_t)t * EF + E_ + node) * NHEADS];
  float acc0 = (lane < 32 ? aself.x : aself.y) * bf2f(hbuf[(size_t)(rbase + node) * H_ + d0]);
  float acc1 = (lane < 32 ? aself.z : aself.w) * bf2f(hbuf[(size_t)(rbase + node) * H_ + d1]);
  const int rs = rowst[node], re = rowst[node + 1];
  for(int i = rs; i < re; i++){
    const int s = csr[i];
    const float4 av = *(const float4*)&alphaC[((size_t)t * EF + i) * NHEADS];
    const float a0 = lane < 32 ? av.x : av.y;
    const float a1 = lane < 32 ? av.z : av.w;
    acc0 += a0 * bf2f(hbuf[(size_t)(rbase + s) * H_ + d0]);
    acc1 += a1 * bf2f(hbuf[(size_t)(rbase + s) * H_ + d1]);
  }
  const float v0 = acc0 + gbias[d0];
  const float v1 = acc1 + gbias[d1];
  spat[(size_t)(rbase + node) * H_ + d0] = f2bf(v0 > 0.f ? v0 : 0.f);
  spat[(size_t)(rbase + node) * H_ + d1] = f2bf(v1 > 0.f ? v1 : 0.f);
}

// ---------------- 2-layer LSTM: LDS-staged weights, software-pipelined phases ----------------
// Per layer-step: 8 phases (2 mats x 4 K-slices). Wave-private weight ring in LDS (no barriers
// for weights): phase q: ds_write slice q+1 (loads 1 phase old -> vmcnt hidden), gload slice q+2,
// ds_read + 8 MFMAs on slice q. Rows padded to 80B: 2-way bank aliasing (free), 16B-aligned b128.
// Register budget by construction ~105 -> no spill.
__global__ __launch_bounds__(512) __attribute__((amdgpu_waves_per_eu(2))) void k_lstm(
    const u16* __restrict__ spat,
    const u16* __restrict__ Wp_ih0, const u16* __restrict__ Wp_hh0,
    const float* __restrict__ bih0, const float* __restrict__ bhh0,
    const u16* __restrict__ Wp_ih1, const u16* __restrict__ Wp_hh1,
    const float* __restrict__ bih1, const float* __restrict__ bhh1,
    float* __restrict__ h1f)
{
  __shared__ __align__(16) unsigned char wbuf[8][2][64 * WROW];  // 80 KB
  __shared__ __align__(16) u16 xin[32 * HPAD];                   // 8.5 KB
  __shared__ __align__(16) u16 h0s[2][32 * HPAD];                // 17 KB
  __shared__ __align__(16) u16 h1s[2][32 * HPAD];                // 17 KB

  const int tid  = threadIdx.x;
  const int wave = tid >> 6;
  const int lane = tid & 63;
  const int l15  = lane & 15;
  const int quad = lane >> 4;
  const int n0   = blockIdx.x * 32;
  const int dim  = wave * 16 + l15;

  for(int i = tid; i < 2 * 32 * HPAD; i += 512){
    ((u16*)h0s)[i] = 0; ((u16*)h1s)[i] = 0;
  }
  // xin(t=0)
  {
    const u16* src = spat + (size_t)n0 * H_;
    #pragma unroll
    for(int it = 0; it < 2; it++){
      const int idx = it * 512 + tid;
      const int r = idx >> 4, c = idx & 15;
      *(uint4*)(xin + r * HPAD + c * 8) = *(const uint4*)(src + r * 128 + c * 8);
    }
  }
  float cst[16];
  #pragma unroll
  for(int i = 0; i < 16; i++) cst[i] = 0.f;

  float bias[2][4];
  #pragma unroll
  for(int g = 0; g < 4; g++){
    bias[0][g] = bih0[g * 128 + dim] + bhh0[g * 128 + dim];
    bias[1][g] = bih1[g * 128 + dim] + bhh1[g * 128 + dim];
  }
  __syncthreads();

  unsigned char* wbuf_w = &wbuf[wave][0][0];
  const size_t grow = (size_t)(wave * 64 + lane) * 128;   // this lane's weight row
  uint4 sA, sB, sC, sD;                                    // staging bank (16 VGPRs)

  #pragma unroll 1
  for(int t = 0; t < T_; t++){
    const int rp = t & 1, wp = rp ^ 1;
    #pragma unroll
    for(int layer = 0; layer < 2; layer++){
      const u16* Wih = layer ? Wp_ih1 : Wp_ih0;
      const u16* Whh = layer ? Wp_hh1 : Wp_hh0;
      const u16* xp  = layer ? h0s[wp] : xin;      // a-input, phases 0-3
      const u16* hp  = layer ? h1s[rp] : h0s[rp];  // a-input, phases 4-7

      f32x4 acc[2][4];
      #pragma unroll
      for(int nt = 0; nt < 4; nt++){
        const float bv = bias[layer][nt];
        f32x4 b4 = {bv, bv, bv, bv};
        acc[0][nt] = b4; acc[1][nt] = b4;
      }

      // prologue: stage slice 0, load slice 1
      {
        const uint* gp = (const uint*)(Wih + grow);
        sA = *(const uint4*)(gp); sB = *(const uint4*)(gp + 4);
        sC = *(const uint4*)(gp + 8); sD = *(const uint4*)(gp + 12);
        unsigned char* wd = wbuf_w + lane * WROW;
        *(uint4*)(wd) = sA; *(uint4*)(wd + 16) = sB;
        *(uint4*)(wd + 32) = sC; *(uint4*)(wd + 48) = sD;
        const uint* gp1 = (const uint*)(Wih + grow + 32);
        sA = *(const uint4*)(gp1); sB = *(const uint4*)(gp1 + 4);
        sC = *(const uint4*)(gp1 + 8); sD = *(const uint4*)(gp1 + 12);
      }

      #pragma unroll 1
      for(int ph = 0; ph < 8; ph++){
        if(ph < 7){   // stage slice ph+1 (its loads are one phase old)
          unsigned char* wd = wbuf_w + ((ph + 1) & 1) * (64 * WROW) + lane * WROW;
          *(uint4*)(wd) = sA; *(uint4*)(wd + 16) = sB;
          *(uint4*)(wd + 32) = sC; *(uint4*)(wd + 48) = sD;
        }
        if(ph < 6){   // load slice ph+2
          const int q2 = ph + 2;
          const u16* m2 = (q2 < 4) ? Wih : Whh;
          const uint* gp = (const uint*)(m2 + grow + (q2 & 3) * 32);
          sA = *(const uint4*)(gp); sB = *(const uint4*)(gp + 4);
          sC = *(const uint4*)(gp + 8); sD = *(const uint4*)(gp + 12);
        }
        // fragments + MFMAs for slice ph
        const u16* ap = (ph < 4) ? xp : hp;
        const int ka = (ph & 3) * 32 + quad * 8;
        const bf16x8 a0 = *(const bf16x8*)(ap + l15 * HPAD + ka);
        const bf16x8 a1 = *(const bf16x8*)(ap + (16 + l15) * HPAD + ka);
        const unsigned char* rb = wbuf_w + (ph & 1) * (64 * WROW);
        #pragma unroll
        for(int nt = 0; nt < 4; nt++){
          const bf16x8 b = *(const bf16x8*)(rb + (nt * 16 + l15) * WROW + quad * 16);
          acc[0][nt] = __builtin_amdgcn_mfma_f32_16x16x32_bf16(a0, b, acc[0][nt], 0, 0, 0);
          acc[1][nt] = __builtin_amdgcn_mfma_f32_16x16x32_bf16(a1, b, acc[1][nt], 0, 0, 0);
        }
      }

      // in-register epilogue: C/D row = quad*4 + r (node), this lane's dim fixed
      u16* hcur = layer ? h1s[wp] : h0s[wp];
      #pragma unroll
      for(int mt = 0; mt < 2; mt++){
        #pragma unroll
        for(int r = 0; r < 4; r++){
          const int node = mt * 16 + quad * 4 + r;
          const float gi = acc[mt][0][r];
          const float gf = acc[mt][1][r];
          const float gg = acc[mt][2][r];
          const float go = acc[mt][3][r];
          const int ci = layer * 8 + mt * 4 + r;
          const float c = sigf(gf) * cst[ci] + sigf(gi) * tanhfast(gg);
          cst[ci] = c;
          const float hv = sigf(go) * tanhfast(c);
          hcur[node * HPAD + dim] = f2bf(hv);
          if(layer == 1 && t == T_ - 1)
            h1f[(size_t)(n0 + node) * H_ + dim] = hv;
        }
      }
      // after layer 1: copy next timestep's x-tile (covered by the barrier below)
      if(layer == 1 && t < T_ - 1){
        const u16* src = spat + (size_t)((t + 1) * NTOT + n0) * H_;
        #pragma unroll
        for(int it = 0; it < 2; it++){
          const int idx = it * 512 + tid;
          const int r = idx >> 4, c = idx & 15;
          *(uint4*)(xin + r * HPAD + c * 8) = *(const uint4*)(src + r * 128 + c * 8);
        }
      }
      __syncthreads();
    }
  }
}

// ---------------- LayerNorm: one wave per node, shuffle-only, fp32 output ----------------
__global__ __launch_bounds__(64) void k_ln(const float* __restrict__ h1f,
    const float* __restrict__ g, const float* __restrict__ b, float* __restrict__ out){
  const int node = blockIdx.x;
  const int tid = threadIdx.x;
  const float v0 = h1f[(size_t)node * H_ + tid];
  const float v1 = h1f[(size_t)node * H_ + 64 + tid];
  float s = v0 + v1;
  #pragma unroll
  for(int m = 32; m >= 1; m >>= 1) s += __shfl_xor(s, m);
  const float mu = s * (1.f / H_);
  const float d0 = v0 - mu, d1 = v1 - mu;
  s = d0 * d0 + d1 * d1;
  #pragma unroll
  for(int m = 32; m >= 1; m >>= 1) s += __shfl_xor(s, m);
  const float rstd = rsqrtf(s * (1.f / H_) + 1e-5f);
  out[(size_t)node * H_ + tid]      = d0 * rstd * g[tid]      + b[tid];
  out[(size_t)node * H_ + 64 + tid] = d1 * rstd * g[64 + tid] + b[64 + tid];
}

extern "C" void kernel_launch(void* const* d_in, const int* in_sizes, int n_in,
                              void* d_out, int out_size, void* d_ws, size_t ws_size,
                              hipStream_t stream) {
  (void)in_sizes; (void)n_in; (void)out_size; (void)ws_size;
  const float* x     = (const float*)d_in[0];
  const float* W     = (const float*)d_in[1];
  const float* att_s = (const float*)d_in[2];
  const float* att_d = (const float*)d_in[3];
  const float* gbias = (const float*)d_in[4];
  const float* Wih0  = (const float*)d_in[5];
  const float* Whh0  = (const float*)d_in[6];
  const float* bih0  = (const float*)d_in[7];
  const float* bhh0  = (const float*)d_in[8];
  const float* Wih1  = (const float*)d_in[9];
  const float* Whh1  = (const float*)d_in[10];
  const float* bih1  = (const float*)d_in[11];
  const float* bhh1  = (const float*)d_in[12];
  const float* lng   = (const float*)d_in[13];
  const float* lnb   = (const float*)d_in[14];
  const int*   ei    = (const int*)d_in[15];
  float* out = (float*)d_out;

  char* p = (char*)d_ws;
  auto carve = [&](size_t bytes) -> void* {
    void* r = (void*)p;
    p += (bytes + 255) & ~(size_t)255;
    return r;
  };
  u16* Wp_ih0 = (u16*)carve(512 * 128 * 2);
  u16* Wp_hh0 = (u16*)carve(512 * 128 * 2);
  u16* Wp_ih1 = (u16*)carve(512 * 128 * 2);
  u16* Wp_hh1 = (u16*)carve(512 * 128 * 2);
  u16* Wt     = (u16*)carve(H_ * F_ * 2);
  u16*   hbuf   = (u16*)carve((size_t)T_ * NTOT * H_ * 2);           // 21 MB bf16
  float* asrc   = (float*)carve((size_t)T_ * NTOT * NHEADS * 4);
  float* adst   = (float*)carve((size_t)T_ * NTOT * NHEADS * 4);
  float* m_     = (float*)carve((size_t)T_ * NTOT * NHEADS * 4);
  float* den_   = (float*)carve((size_t)T_ * NTOT * NHEADS * 4);
  float* alphaC = (float*)carve((size_t)T_ * EF * NHEADS * 4);       // 11.8 MB
  float* h1f    = (float*)carve((size_t)NTOT * H_ * 4);
  u16*   spat   = (u16*)carve((size_t)T_ * NTOT * H_ * 2);           // 21 MB bf16
  int*   cnt    = (int*)carve(NTOT * 4);
  int*   curs   = (int*)carve(NTOT * 4);
  int*   rowst  = (int*)carve((NTOT + 1) * 4);
  int*   csr    = (int*)carve((size_t)E_ * 4);
  int*   csrd   = (int*)carve((size_t)E_ * 4);

  hipLaunchKernelGGL(k_init,  dim3(32),        dim3(256),  0, stream, cnt);
  hipLaunchKernelGGL(k_count, dim3(256),       dim3(256),  0, stream, ei, cnt);
  hipLaunchKernelGGL(k_scan,  dim3(1),         dim3(1024), 0, stream, cnt, rowst, curs);
  hipLaunchKernelGGL(k_fill,  dim3(256),       dim3(256),  0, stream, ei, rowst, curs, csr, csrd);
  hipLaunchKernelGGL(k_wperm, dim3(256, 4),    dim3(256),  0, stream,
                     Wih0, Wp_ih0, Whh0, Wp_hh0, Wih1, Wp_ih1, Whh1, Wp_hh1);
  hipLaunchKernelGGL(k_wtc,   dim3(32),        dim3(256),  0, stream, W, Wt);
  hipLaunchKernelGGL(k_projm, dim3(1280),      dim3(256),  0, stream, x, Wt, att_s, att_d, hbuf, asrc, adst);
  hipLaunchKernelGGL(k_mden,  dim3(1280),      dim3(256),  0, stream, asrc, adst, rowst, csr, m_, den_);
  hipLaunchKernelGGL(k_alpha, dim3(288, 10),   dim3(256),  0, stream, asrc, adst, csr, csrd, m_, den_, alphaC);
  hipLaunchKernelGGL(k_agg,   dim3(20480),     dim3(256),  0, stream, hbuf, alphaC, rowst, csr, gbias, spat);
  hipLaunchKernelGGL(k_lstm,  dim3(256),       dim3(512),  0, stream, spat,
                     Wp_ih0, Wp_hh0, bih0, bhh0, Wp_ih1, Wp_hh1, bih1, bhh1, h1f);
  hipLaunchKernelGGL(k_ln,    dim3(8192),      dim3(64),   0, stream, h1f, lng, lnb, out);
}